// Round 1
// baseline (3513.004 us; speedup 1.0000x reference)
//
#include <hip/hip_runtime.h>
#include <stdint.h>

// sample_and_group: B=8 N=8192 C=64 S=2048 K=32 OUT=128
// out = (out[8,2048,128], sampled_coor[8,2048,3]) concatenated in d_out (float32).
//
// Pipeline: kprep (transpose w1/w2 -> wt[i][o], gather sampled_coor)
//           kknn  (exact top-32 by (dist,idx) u64 key, bit-exact numpy dist order)
//           kphase<1> (y1 = feat@w1+b1 -> channel sum/sumsq partials)
//           kreduce   (double-precision finalize -> scale1/shift1)
//           kphase<2> (y1 -> bn1+relu -> y2 -> sum/sumsq partials + per-group max_k y2)
//           kreduce   (-> scale2/shift2)
//           kout      (out = relu(scale2*max + shift2); valid since scale2>0 => monotone)
//
// Workspace layout (bytes), total ~14.2 MB:
//   [0,2MB)        knn indices  int32[16384*32]
//   [2MB,10MB)     m = max_k y2 f32[16384*128]
//   [10MB,12MB)    partials1    f32[2048*256]  (per block: 128 sums + 128 sumsqs)
//   [12MB,14MB)    partials2    f32[2048*256]
//   [14MB,+64KB)   wt1 (w1 transposed, [i][o])
//   [.. ,+64KB)    wt2
//   [.. ,+1KB)     stats1 (scale[128], shift[128])
//   [.. ,+1KB)     stats2

#define N_    8192
#define GPB_  8       // groups per block in phase kernels

__device__ __forceinline__ float f4e(const float4 v, int j) {
  return j == 0 ? v.x : j == 1 ? v.y : j == 2 ? v.z : v.w;
}

// ---------------- prep: weight transpose + sampled_coor gather ----------------
__global__ __launch_bounds__(256) void kprep(const float* __restrict__ w1,
                                             const float* __restrict__ w2,
                                             const float* __restrict__ coor,
                                             const int* __restrict__ indx,
                                             float* __restrict__ wt1,
                                             float* __restrict__ wt2,
                                             float* __restrict__ outc) {
  int e = blockIdx.x * 256 + threadIdx.x;   // grid is exactly 320*256 = 81920
  if (e < 16384) {
    int i = e >> 7, o = e & 127;
    wt1[e] = w1[o * 128 + i];
  } else if (e < 32768) {
    int e2 = e - 16384;
    int i = e2 >> 7, o = e2 & 127;
    wt2[e2] = w2[o * 128 + i];
  } else {
    int e2 = e - 32768;                      // 0..49151
    int bs = e2 / 3, c = e2 - bs * 3;
    int b = bs >> 11, s = bs & 2047;
    outc[e2] = coor[(b * N_ + indx[s]) * 3 + c];
  }
}

// ---------------- KNN: one wave per query, per-lane sorted top-16 + merge ----
// Key = (dist_bits << 32) | point_idx : min-order == (dist asc, idx asc), exactly
// matching stable top_k(-dist). dist computed with __f*_rn to forbid FMA
// contraction -> bit-identical to numpy ((dx*dx+dy*dy)+dz*dz).
// Per-lane 16 slots is safe: P(one lane of 64 owns >16 of the true top-32) ~ 1e-16.
__global__ __launch_bounds__(64) void kknn(const float* __restrict__ coor,
                                           const int* __restrict__ indx,
                                           int* __restrict__ knn) {
  __shared__ unsigned long long mbuf[64 * 16];
  const int gid = blockIdx.x;
  const int b = gid >> 11, s = gid & 2047;
  const int lane = threadIdx.x;
  const float* cb = coor + (size_t)b * (N_ * 3);
  const int qi = indx[s];
  const float qx = cb[qi * 3 + 0], qy = cb[qi * 3 + 1], qz = cb[qi * 3 + 2];

  unsigned long long kb[16];
#pragma unroll
  for (int j = 0; j < 16; ++j) kb[j] = ~0ULL;

  for (int it = 0; it < 128; ++it) {
    const int p = lane + (it << 6);
    const float px = cb[p * 3 + 0], py = cb[p * 3 + 1], pz = cb[p * 3 + 2];
    const float dx = __fsub_rn(px, qx);
    const float dy = __fsub_rn(py, qy);
    const float dz = __fsub_rn(pz, qz);
    const float dist =
        __fadd_rn(__fadd_rn(__fmul_rn(dx, dx), __fmul_rn(dy, dy)), __fmul_rn(dz, dz));
    unsigned long long key =
        ((unsigned long long)__float_as_uint(dist) << 32) | (unsigned int)p;
    if (key < kb[15]) {                       // sorted insertion (branchless chain)
#pragma unroll
      for (int j = 0; j < 16; ++j) {
        const unsigned long long lo = key < kb[j] ? key : kb[j];
        const unsigned long long hi = key < kb[j] ? kb[j] : key;
        kb[j] = lo;
        key = hi;
      }
    }
  }
#pragma unroll
  for (int j = 0; j < 16; ++j) mbuf[lane * 16 + j] = kb[j];
  __syncthreads();

  // 32x extract-min across the wave's 64 sorted lists
  unsigned long long cur = kb[0];
  int ptr = 1;
  unsigned int myidx = 0;
  for (int j = 0; j < 32; ++j) {
    unsigned long long red = cur;
#pragma unroll
    for (int off = 32; off > 0; off >>= 1) {
      const unsigned long long other = __shfl_xor(red, off, 64);
      red = other < red ? other : red;
    }
    if (lane == j) myidx = (unsigned int)red;       // low 32 bits = point index
    const unsigned long long ball = __ballot(cur == red);  // keys unique -> 1 lane
    const int src = (int)__builtin_ctzll(ball);
    if (lane == src) {
      cur = (ptr < 16) ? mbuf[lane * 16 + ptr] : ~0ULL;
      ++ptr;
    }
  }
  if (lane < 32) knn[gid * 32 + lane] = (int)myidx;
}

// ---------------- phase kernels: per-group fused GEMMs -----------------------
// feat[k] = [sx, d_k] with sx row-constant => y1[k][o] = base[o] + sum_i d_k[i]*wt1[64+i][o]
template <int PHASE>
__global__ __launch_bounds__(256) void kphase(
    const float* __restrict__ x, const int* __restrict__ indx,
    const int* __restrict__ knn, const float* __restrict__ wt1,
    const float* __restrict__ b1, const float* __restrict__ wt2,
    const float* __restrict__ b2, const float* __restrict__ st1,
    float* __restrict__ part, float* __restrict__ mout) {
  __shared__ __align__(16) float sx[64];
  __shared__ int nbi[32];
  __shared__ __align__(16) float dls[32 * 64];
  __shared__ __align__(16) float basels[128];
  __shared__ __align__(16) float h1ls[PHASE == 2 ? 32 * 128 : 4];
  __shared__ __align__(16) float red[8 * 128];

  const int tid = threadIdx.x;
  const int otile = tid & 31, rtile = tid >> 5;   // 32 x 8 thread tiles
  const int o0 = otile * 4, r0 = rtile * 4;       // 4x4 register tile each

  float sAcc[4] = {0.f, 0.f, 0.f, 0.f};
  float ssAcc[4] = {0.f, 0.f, 0.f, 0.f};
  float s1v[4], t1v[4], b2v[4];
  if constexpr (PHASE == 2) {
#pragma unroll
    for (int j = 0; j < 4; ++j) {
      s1v[j] = st1[o0 + j];
      t1v[j] = st1[128 + o0 + j];
      b2v[j] = b2[o0 + j];
    }
  }
  (void)b2; (void)st1; (void)mout; (void)wt2;

  for (int g = 0; g < GPB_; ++g) {
    const int gid = blockIdx.x * GPB_ + g;
    const int b = gid >> 11, s = gid & 2047;
    const float* xb = x + (size_t)b * (N_ * 64);
    __syncthreads();                              // protect LDS reuse
    if (tid < 64) sx[tid] = xb[indx[s] * 64 + tid];
    if (tid >= 64 && tid < 96) nbi[tid - 64] = knn[gid * 32 + (tid - 64)];
    __syncthreads();
#pragma unroll
    for (int j = 0; j < 8; ++j) {                 // stage d = knn_x - sx (coalesced)
      const int e = tid + 256 * j;
      const int row = e >> 6, col = e & 63;
      dls[e] = xb[nbi[row] * 64 + col] - sx[col];
    }
    if (tid < 128) {                              // base[o] = b1[o] + sx . w1[o][0:64]
      float a = b1[tid];
      for (int i = 0; i < 64; ++i) a = fmaf(sx[i], wt1[i * 128 + tid], a);
      basels[tid] = a;
    }
    __syncthreads();

    float acc[4][4];
    {
      const float4 bb = *(const float4*)&basels[o0];
#pragma unroll
      for (int rr = 0; rr < 4; ++rr) {
        acc[rr][0] = bb.x; acc[rr][1] = bb.y; acc[rr][2] = bb.z; acc[rr][3] = bb.w;
      }
    }
    for (int i = 0; i < 64; i += 4) {             // layer-1 GEMM (K=64)
      float4 dv[4], wv[4];
#pragma unroll
      for (int rr = 0; rr < 4; ++rr) dv[rr] = *(const float4*)&dls[(r0 + rr) * 64 + i];
#pragma unroll
      for (int ii = 0; ii < 4; ++ii) wv[ii] = *(const float4*)&wt1[(64 + i + ii) * 128 + o0];
#pragma unroll
      for (int ii = 0; ii < 4; ++ii)
#pragma unroll
        for (int rr = 0; rr < 4; ++rr) {
          const float dval = f4e(dv[rr], ii);
          acc[rr][0] = fmaf(dval, wv[ii].x, acc[rr][0]);
          acc[rr][1] = fmaf(dval, wv[ii].y, acc[rr][1]);
          acc[rr][2] = fmaf(dval, wv[ii].z, acc[rr][2]);
          acc[rr][3] = fmaf(dval, wv[ii].w, acc[rr][3]);
        }
    }

    if constexpr (PHASE == 1) {
#pragma unroll
      for (int jj = 0; jj < 4; ++jj)
#pragma unroll
        for (int rr = 0; rr < 4; ++rr) {
          const float v = acc[rr][jj];
          sAcc[jj] += v;
          ssAcc[jj] = fmaf(v, v, ssAcc[jj]);
        }
    } else {
      // bn1 + relu -> h1 in LDS
#pragma unroll
      for (int rr = 0; rr < 4; ++rr) {
        float4 hv;
        hv.x = fmaxf(0.f, fmaf(acc[rr][0], s1v[0], t1v[0]));
        hv.y = fmaxf(0.f, fmaf(acc[rr][1], s1v[1], t1v[1]));
        hv.z = fmaxf(0.f, fmaf(acc[rr][2], s1v[2], t1v[2]));
        hv.w = fmaxf(0.f, fmaf(acc[rr][3], s1v[3], t1v[3]));
        *(float4*)&h1ls[(r0 + rr) * 128 + o0] = hv;
      }
      __syncthreads();
      float acc2[4][4];
#pragma unroll
      for (int rr = 0; rr < 4; ++rr) {
        acc2[rr][0] = b2v[0]; acc2[rr][1] = b2v[1];
        acc2[rr][2] = b2v[2]; acc2[rr][3] = b2v[3];
      }
      for (int i = 0; i < 128; i += 4) {          // layer-2 GEMM (K=128)
        float4 hv[4], wv[4];
#pragma unroll
        for (int rr = 0; rr < 4; ++rr) hv[rr] = *(const float4*)&h1ls[(r0 + rr) * 128 + i];
#pragma unroll
        for (int ii = 0; ii < 4; ++ii) wv[ii] = *(const float4*)&wt2[(i + ii) * 128 + o0];
#pragma unroll
        for (int ii = 0; ii < 4; ++ii)
#pragma unroll
          for (int rr = 0; rr < 4; ++rr) {
            const float hval = f4e(hv[rr], ii);
            acc2[rr][0] = fmaf(hval, wv[ii].x, acc2[rr][0]);
            acc2[rr][1] = fmaf(hval, wv[ii].y, acc2[rr][1]);
            acc2[rr][2] = fmaf(hval, wv[ii].z, acc2[rr][2]);
            acc2[rr][3] = fmaf(hval, wv[ii].w, acc2[rr][3]);
          }
      }
#pragma unroll
      for (int jj = 0; jj < 4; ++jj)              // stats of y2 (pre-BN2)
#pragma unroll
        for (int rr = 0; rr < 4; ++rr) {
          const float v = acc2[rr][jj];
          sAcc[jj] += v;
          ssAcc[jj] = fmaf(v, v, ssAcc[jj]);
        }
      float4 mv;                                  // per-group max over k rows
      mv.x = fmaxf(fmaxf(acc2[0][0], acc2[1][0]), fmaxf(acc2[2][0], acc2[3][0]));
      mv.y = fmaxf(fmaxf(acc2[0][1], acc2[1][1]), fmaxf(acc2[2][1], acc2[3][1]));
      mv.z = fmaxf(fmaxf(acc2[0][2], acc2[1][2]), fmaxf(acc2[2][2], acc2[3][2]));
      mv.w = fmaxf(fmaxf(acc2[0][3], acc2[1][3]), fmaxf(acc2[2][3], acc2[3][3]));
      *(float4*)&red[rtile * 128 + o0] = mv;
      __syncthreads();
      if (tid < 128) {
        float mm = red[tid];
#pragma unroll
        for (int rt = 1; rt < 8; ++rt) mm = fmaxf(mm, red[rt * 128 + tid]);
        mout[(size_t)gid * 128 + tid] = mm;
      }
    }
  }

  // block-level channel reduction of sums -> partials
  __syncthreads();
  *(float4*)&red[rtile * 128 + o0] = make_float4(sAcc[0], sAcc[1], sAcc[2], sAcc[3]);
  __syncthreads();
  if (tid < 128) {
    float t = red[tid];
#pragma unroll
    for (int rt = 1; rt < 8; ++rt) t += red[rt * 128 + tid];
    part[blockIdx.x * 256 + tid] = t;
  }
  __syncthreads();
  *(float4*)&red[rtile * 128 + o0] = make_float4(ssAcc[0], ssAcc[1], ssAcc[2], ssAcc[3]);
  __syncthreads();
  if (tid < 128) {
    float t = red[tid];
#pragma unroll
    for (int rt = 1; rt < 8; ++rt) t += red[rt * 128 + tid];
    part[blockIdx.x * 256 + 128 + tid] = t;
  }
}

// ---------------- stats finalize (double precision) --------------------------
__global__ __launch_bounds__(1024) void kreduce(const float* __restrict__ part,
                                                const float* __restrict__ gam,
                                                const float* __restrict__ bet,
                                                float* __restrict__ st) {
  __shared__ double redd[4][256];
  const int tid = threadIdx.x;
  const int c = tid & 255, pq = tid >> 8;
  double acc = 0.0;
  for (int row = pq; row < 2048; row += 4) acc += (double)part[row * 256 + c];
  redd[pq][c] = acc;
  __syncthreads();
  if (tid < 256) redd[0][tid] = redd[0][tid] + redd[1][tid] + redd[2][tid] + redd[3][tid];
  __syncthreads();
  if (tid < 128) {
    const double Sv = redd[0][tid], SSv = redd[0][128 + tid];
    const double cnt = 524288.0;                 // B*S*K
    const double mean = Sv / cnt;
    const double var = SSv / cnt - mean * mean;
    const double scale = (double)gam[tid] / sqrt(var + 1e-5);
    st[tid] = (float)scale;
    st[128 + tid] = (float)((double)bet[tid] - mean * scale);
  }
}

// ---------------- final: out = relu(scale2 * max_k(y2) + shift2) -------------
__global__ __launch_bounds__(256) void kout(const float* __restrict__ m,
                                            const float* __restrict__ st2,
                                            float* __restrict__ out) {
  const int e4 = blockIdx.x * 256 + threadIdx.x;  // 524288 float4s
  const int o0 = (e4 & 31) * 4;
  const float4 v = ((const float4*)m)[e4];
  const float4 sc = *(const float4*)&st2[o0];
  const float4 sh = *(const float4*)&st2[128 + o0];
  float4 r;
  r.x = fmaxf(0.f, fmaf(v.x, sc.x, sh.x));
  r.y = fmaxf(0.f, fmaf(v.y, sc.y, sh.y));
  r.z = fmaxf(0.f, fmaf(v.z, sc.z, sh.z));
  r.w = fmaxf(0.f, fmaf(v.w, sc.w, sh.w));
  ((float4*)out)[e4] = r;
}

extern "C" void kernel_launch(void* const* d_in, const int* in_sizes, int n_in,
                              void* d_out, int out_size, void* d_ws, size_t ws_size,
                              hipStream_t stream) {
  (void)in_sizes; (void)n_in; (void)out_size; (void)ws_size;
  const float* x    = (const float*)d_in[0];
  const float* coor = (const float*)d_in[1];
  const int*   indx = (const int*)d_in[2];
  const float* w1   = (const float*)d_in[3];
  const float* b1   = (const float*)d_in[4];
  const float* g1   = (const float*)d_in[5];
  const float* be1  = (const float*)d_in[6];
  const float* w2   = (const float*)d_in[7];
  const float* b2   = (const float*)d_in[8];
  const float* g2   = (const float*)d_in[9];
  const float* be2  = (const float*)d_in[10];
  float* out = (float*)d_out;

  char* ws = (char*)d_ws;
  int*   knn   = (int*)(ws + 0);
  float* mbuf  = (float*)(ws + 2097152);
  float* part1 = (float*)(ws + 10485760);
  float* part2 = (float*)(ws + 12582912);
  float* wt1   = (float*)(ws + 14680064);
  float* wt2   = (float*)(ws + 14745600);
  float* st1   = (float*)(ws + 14811136);
  float* st2   = (float*)(ws + 14812160);

  float* outc = out + 2097152;   // sampled_coor region of d_out

  kprep<<<320, 256, 0, stream>>>(w1, w2, coor, indx, wt1, wt2, outc);
  kknn<<<16384, 64, 0, stream>>>(coor, indx, knn);
  kphase<1><<<2048, 256, 0, stream>>>(x, indx, knn, wt1, b1, wt2, b2, nullptr, part1, nullptr);
  kreduce<<<1, 1024, 0, stream>>>(part1, g1, be1, st1);
  kphase<2><<<2048, 256, 0, stream>>>(x, indx, knn, wt1, b1, wt2, b2, st1, part2, mbuf);
  kreduce<<<1, 1024, 0, stream>>>(part2, g2, be2, st2);
  kout<<<2048, 256, 0, stream>>>(mbuf, st2, out);
}

// Round 2
// 1444.258 us; speedup vs baseline: 2.4324x; 2.4324x over previous
//
#include <hip/hip_runtime.h>
#include <stdint.h>

// sample_and_group: B=8 N=8192 C=64 S=2048 K=32 OUT=128
// out = (out[8,2048,128], sampled_coor[8,2048,3]) concatenated in d_out (float32).
//
// Pipeline: kprep (transpose w1/w2 -> wt[i][o], gather sampled_coor)
//           kknn  (exact top-32 by (dist,idx) u64 key, bit-exact numpy dist order)
//           kphase<1> (y1 = feat@w1+b1 -> channel sum/sumsq partials)
//           kreduce   (double-precision finalize -> scale1/shift1)
//           kphase<2> (y1 -> bn1+relu -> y2 -> sum/sumsq partials + per-group max_k y2)
//           kreduce   (-> scale2/shift2)
//           kout      (out = relu(scale2*max + shift2); valid since scale2>0 => monotone)
//
// R1 fix: phase kernels were SPILL-BOUND (VGPR=256 + ~330MB scratch writes/dispatch).
// Unroll control (#pragma unroll 1 on group loop, unroll 2 on K-loops) +
// __launch_bounds__(256,4) to cap VGPRs at 128, float4 gather staging, and a
// parallelized base[] dot product.
//
// Workspace layout (bytes), total ~14.2 MB:
//   [0,2MB)        knn indices  int32[16384*32]
//   [2MB,10MB)     m = max_k y2 f32[16384*128]
//   [10MB,12MB)    partials1    f32[2048*256]  (per block: 128 sums + 128 sumsqs)
//   [12MB,14MB)    partials2    f32[2048*256]
//   [14MB,+64KB)   wt1 (w1 transposed, [i][o])
//   [.. ,+64KB)    wt2
//   [.. ,+1KB)     stats1 (scale[128], shift[128])
//   [.. ,+1KB)     stats2

#define N_    8192
#define GPB_  8       // groups per block in phase kernels

__device__ __forceinline__ float f4e(const float4 v, int j) {
  return j == 0 ? v.x : j == 1 ? v.y : j == 2 ? v.z : v.w;
}

// ---------------- prep: weight transpose + sampled_coor gather ----------------
__global__ __launch_bounds__(256) void kprep(const float* __restrict__ w1,
                                             const float* __restrict__ w2,
                                             const float* __restrict__ coor,
                                             const int* __restrict__ indx,
                                             float* __restrict__ wt1,
                                             float* __restrict__ wt2,
                                             float* __restrict__ outc) {
  int e = blockIdx.x * 256 + threadIdx.x;   // grid is exactly 320*256 = 81920
  if (e < 16384) {
    int i = e >> 7, o = e & 127;
    wt1[e] = w1[o * 128 + i];
  } else if (e < 32768) {
    int e2 = e - 16384;
    int i = e2 >> 7, o = e2 & 127;
    wt2[e2] = w2[o * 128 + i];
  } else {
    int e2 = e - 32768;                      // 0..49151
    int bs = e2 / 3, c = e2 - bs * 3;
    int b = bs >> 11, s = bs & 2047;
    outc[e2] = coor[(b * N_ + indx[s]) * 3 + c];
  }
}

// ---------------- KNN: one wave per query, per-lane sorted top-16 + merge ----
// Key = (dist_bits << 32) | point_idx : min-order == (dist asc, idx asc), exactly
// matching stable top_k(-dist). dist computed with __f*_rn to forbid FMA
// contraction -> bit-identical to numpy ((dx*dx+dy*dy)+dz*dz).
__global__ __launch_bounds__(64) void kknn(const float* __restrict__ coor,
                                           const int* __restrict__ indx,
                                           int* __restrict__ knn) {
  __shared__ unsigned long long mbuf[64 * 16];
  const int gid = blockIdx.x;
  const int b = gid >> 11, s = gid & 2047;
  const int lane = threadIdx.x;
  const float* cb = coor + (size_t)b * (N_ * 3);
  const int qi = indx[s];
  const float qx = cb[qi * 3 + 0], qy = cb[qi * 3 + 1], qz = cb[qi * 3 + 2];

  unsigned long long kb[16];
#pragma unroll
  for (int j = 0; j < 16; ++j) kb[j] = ~0ULL;

  for (int it = 0; it < 128; ++it) {
    const int p = lane + (it << 6);
    const float px = cb[p * 3 + 0], py = cb[p * 3 + 1], pz = cb[p * 3 + 2];
    const float dx = __fsub_rn(px, qx);
    const float dy = __fsub_rn(py, qy);
    const float dz = __fsub_rn(pz, qz);
    const float dist =
        __fadd_rn(__fadd_rn(__fmul_rn(dx, dx), __fmul_rn(dy, dy)), __fmul_rn(dz, dz));
    unsigned long long key =
        ((unsigned long long)__float_as_uint(dist) << 32) | (unsigned int)p;
    if (key < kb[15]) {                       // sorted insertion
#pragma unroll
      for (int j = 0; j < 16; ++j) {
        const unsigned long long lo = key < kb[j] ? key : kb[j];
        const unsigned long long hi = key < kb[j] ? kb[j] : key;
        kb[j] = lo;
        key = hi;
      }
    }
  }
#pragma unroll
  for (int j = 0; j < 16; ++j) mbuf[lane * 16 + j] = kb[j];
  __syncthreads();

  // 32x extract-min across the wave's 64 sorted lists
  unsigned long long cur = kb[0];
  int ptr = 1;
  unsigned int myidx = 0;
  for (int j = 0; j < 32; ++j) {
    unsigned long long red = cur;
#pragma unroll
    for (int off = 32; off > 0; off >>= 1) {
      const unsigned long long other = __shfl_xor(red, off, 64);
      red = other < red ? other : red;
    }
    if (lane == j) myidx = (unsigned int)red;
    const unsigned long long ball = __ballot(cur == red);  // keys unique -> 1 lane
    const int src = (int)__builtin_ctzll(ball);
    if (lane == src) {
      cur = (ptr < 16) ? mbuf[lane * 16 + ptr] : ~0ULL;
      ++ptr;
    }
  }
  if (lane < 32) knn[gid * 32 + lane] = (int)myidx;
}

// ---------------- phase kernels: per-group fused GEMMs -----------------------
// feat[k] = [sx, d_k] with sx row-constant => y1[k][o] = base[o] + sum_i d_k[i]*wt1[64+i][o]
template <int PHASE>
__global__ __launch_bounds__(256, 4) void kphase(
    const float* __restrict__ x, const int* __restrict__ indx,
    const int* __restrict__ knn, const float* __restrict__ wt1,
    const float* __restrict__ b1, const float* __restrict__ wt2,
    const float* __restrict__ b2, const float* __restrict__ st1,
    float* __restrict__ part, float* __restrict__ mout) {
  __shared__ __align__(16) float sx[64];
  __shared__ int nbi[32];
  __shared__ __align__(16) float dls[32 * 64];
  __shared__ __align__(16) float h1ls[PHASE == 2 ? 32 * 128 : 4];
  __shared__ __align__(16) float red[8 * 128];

  const int tid = threadIdx.x;
  const int otile = tid & 31, rtile = tid >> 5;   // 32 x 8 thread tiles
  const int o0 = otile * 4, r0 = rtile * 4;       // 4x4 register tile each
  const int bo = tid & 127, bh = tid >> 7;        // base-dot split: channel, half

  float4* const dls4 = (float4*)dls;

  float sAcc[4] = {0.f, 0.f, 0.f, 0.f};
  float ssAcc[4] = {0.f, 0.f, 0.f, 0.f};
  float s1v[4], t1v[4], b2v[4];
  if constexpr (PHASE == 2) {
#pragma unroll
    for (int j = 0; j < 4; ++j) {
      s1v[j] = st1[o0 + j];
      t1v[j] = st1[128 + o0 + j];
      b2v[j] = b2[o0 + j];
    }
  }
  (void)b2; (void)st1; (void)mout; (void)wt2;
  const float b1v = (bh == 0) ? b1[bo] : 0.f;

#pragma unroll 1
  for (int g = 0; g < GPB_; ++g) {
    const int gid = blockIdx.x * GPB_ + g;
    const int b = gid >> 11, s = gid & 2047;
    const float* xb = x + (size_t)b * (N_ * 64);
    __syncthreads();                              // protect LDS reuse
    if (tid < 64) sx[tid] = xb[indx[s] * 64 + tid];
    if (tid >= 64 && tid < 96) nbi[tid - 64] = knn[gid * 32 + (tid - 64)];
    __syncthreads();
    // stage d = knn_x - sx as float4 (coalesced 16B/lane, 4 rows per wave)
#pragma unroll
    for (int j = 0; j < 2; ++j) {
      const int e4 = tid + 256 * j;               // 0..511 float4s
      const int row = e4 >> 4, col4 = e4 & 15;
      const float4 xv = *(const float4*)&xb[(size_t)nbi[row] * 64 + col4 * 4];
      const float4 sv = ((const float4*)sx)[col4];
      float4 dv;
      dv.x = xv.x - sv.x; dv.y = xv.y - sv.y; dv.z = xv.z - sv.z; dv.w = xv.w - sv.w;
      dls4[row * 16 + col4] = dv;
    }
    // base half-dots: thread -> channel bo, i-range [bh*32, bh*32+32)
    {
      float a = b1v;
#pragma unroll 8
      for (int i = 0; i < 32; ++i) {
        const int ii = bh * 32 + i;
        a = fmaf(sx[ii], wt1[ii * 128 + bo], a);
      }
      red[tid] = a;                               // rows 0..1 of red
    }
    __syncthreads();

    float acc[4][4];
    {
      const float4 blo = *(const float4*)&red[o0];
      const float4 bhi = *(const float4*)&red[128 + o0];
#pragma unroll
      for (int rr = 0; rr < 4; ++rr) {
        acc[rr][0] = blo.x + bhi.x; acc[rr][1] = blo.y + bhi.y;
        acc[rr][2] = blo.z + bhi.z; acc[rr][3] = blo.w + bhi.w;
      }
    }
#pragma unroll 2
    for (int i = 0; i < 64; i += 4) {             // layer-1 GEMM (K=64)
      float4 dv[4], wv[4];
#pragma unroll
      for (int rr = 0; rr < 4; ++rr) dv[rr] = dls4[(r0 + rr) * 16 + (i >> 2)];
#pragma unroll
      for (int ii = 0; ii < 4; ++ii) wv[ii] = *(const float4*)&wt1[(64 + i + ii) * 128 + o0];
#pragma unroll
      for (int ii = 0; ii < 4; ++ii)
#pragma unroll
        for (int rr = 0; rr < 4; ++rr) {
          const float dval = f4e(dv[rr], ii);
          acc[rr][0] = fmaf(dval, wv[ii].x, acc[rr][0]);
          acc[rr][1] = fmaf(dval, wv[ii].y, acc[rr][1]);
          acc[rr][2] = fmaf(dval, wv[ii].z, acc[rr][2]);
          acc[rr][3] = fmaf(dval, wv[ii].w, acc[rr][3]);
        }
    }

    if constexpr (PHASE == 1) {
#pragma unroll
      for (int jj = 0; jj < 4; ++jj)
#pragma unroll
        for (int rr = 0; rr < 4; ++rr) {
          const float v = acc[rr][jj];
          sAcc[jj] += v;
          ssAcc[jj] = fmaf(v, v, ssAcc[jj]);
        }
    } else {
      // bn1 + relu -> h1 in LDS
#pragma unroll
      for (int rr = 0; rr < 4; ++rr) {
        float4 hv;
        hv.x = fmaxf(0.f, fmaf(acc[rr][0], s1v[0], t1v[0]));
        hv.y = fmaxf(0.f, fmaf(acc[rr][1], s1v[1], t1v[1]));
        hv.z = fmaxf(0.f, fmaf(acc[rr][2], s1v[2], t1v[2]));
        hv.w = fmaxf(0.f, fmaf(acc[rr][3], s1v[3], t1v[3]));
        *(float4*)&h1ls[(r0 + rr) * 128 + o0] = hv;
      }
      __syncthreads();
      float acc2[4][4];
#pragma unroll
      for (int rr = 0; rr < 4; ++rr) {
        acc2[rr][0] = b2v[0]; acc2[rr][1] = b2v[1];
        acc2[rr][2] = b2v[2]; acc2[rr][3] = b2v[3];
      }
#pragma unroll 2
      for (int i = 0; i < 128; i += 4) {          // layer-2 GEMM (K=128)
        float4 hv[4], wv[4];
#pragma unroll
        for (int rr = 0; rr < 4; ++rr) hv[rr] = *(const float4*)&h1ls[(r0 + rr) * 128 + i];
#pragma unroll
        for (int ii = 0; ii < 4; ++ii) wv[ii] = *(const float4*)&wt2[(i + ii) * 128 + o0];
#pragma unroll
        for (int ii = 0; ii < 4; ++ii)
#pragma unroll
          for (int rr = 0; rr < 4; ++rr) {
            const float hval = f4e(hv[rr], ii);
            acc2[rr][0] = fmaf(hval, wv[ii].x, acc2[rr][0]);
            acc2[rr][1] = fmaf(hval, wv[ii].y, acc2[rr][1]);
            acc2[rr][2] = fmaf(hval, wv[ii].z, acc2[rr][2]);
            acc2[rr][3] = fmaf(hval, wv[ii].w, acc2[rr][3]);
          }
      }
#pragma unroll
      for (int jj = 0; jj < 4; ++jj)              // stats of y2 (pre-BN2)
#pragma unroll
        for (int rr = 0; rr < 4; ++rr) {
          const float v = acc2[rr][jj];
          sAcc[jj] += v;
          ssAcc[jj] = fmaf(v, v, ssAcc[jj]);
        }
      float4 mv;                                  // per-group max over k rows
      mv.x = fmaxf(fmaxf(acc2[0][0], acc2[1][0]), fmaxf(acc2[2][0], acc2[3][0]));
      mv.y = fmaxf(fmaxf(acc2[0][1], acc2[1][1]), fmaxf(acc2[2][1], acc2[3][1]));
      mv.z = fmaxf(fmaxf(acc2[0][2], acc2[1][2]), fmaxf(acc2[2][2], acc2[3][2]));
      mv.w = fmaxf(fmaxf(acc2[0][3], acc2[1][3]), fmaxf(acc2[2][3], acc2[3][3]));
      *(float4*)&red[rtile * 128 + o0] = mv;
      __syncthreads();
      if (tid < 128) {
        float mm = red[tid];
#pragma unroll
        for (int rt = 1; rt < 8; ++rt) mm = fmaxf(mm, red[rt * 128 + tid]);
        mout[(size_t)gid * 128 + tid] = mm;
      }
    }
  }

  // block-level channel reduction of sums -> partials
  __syncthreads();
  *(float4*)&red[rtile * 128 + o0] = make_float4(sAcc[0], sAcc[1], sAcc[2], sAcc[3]);
  __syncthreads();
  if (tid < 128) {
    float t = red[tid];
#pragma unroll
    for (int rt = 1; rt < 8; ++rt) t += red[rt * 128 + tid];
    part[blockIdx.x * 256 + tid] = t;
  }
  __syncthreads();
  *(float4*)&red[rtile * 128 + o0] = make_float4(ssAcc[0], ssAcc[1], ssAcc[2], ssAcc[3]);
  __syncthreads();
  if (tid < 128) {
    float t = red[tid];
#pragma unroll
    for (int rt = 1; rt < 8; ++rt) t += red[rt * 128 + tid];
    part[blockIdx.x * 256 + 128 + tid] = t;
  }
}

// ---------------- stats finalize (double precision) --------------------------
__global__ __launch_bounds__(1024) void kreduce(const float* __restrict__ part,
                                                const float* __restrict__ gam,
                                                const float* __restrict__ bet,
                                                float* __restrict__ st) {
  __shared__ double redd[4][256];
  const int tid = threadIdx.x;
  const int c = tid & 255, pq = tid >> 8;
  double acc = 0.0;
  for (int row = pq; row < 2048; row += 4) acc += (double)part[row * 256 + c];
  redd[pq][c] = acc;
  __syncthreads();
  if (tid < 256) redd[0][tid] = redd[0][tid] + redd[1][tid] + redd[2][tid] + redd[3][tid];
  __syncthreads();
  if (tid < 128) {
    const double Sv = redd[0][tid], SSv = redd[0][128 + tid];
    const double cnt = 524288.0;                 // B*S*K
    const double mean = Sv / cnt;
    const double var = SSv / cnt - mean * mean;
    const double scale = (double)gam[tid] / sqrt(var + 1e-5);
    st[tid] = (float)scale;
    st[128 + tid] = (float)((double)bet[tid] - mean * scale);
  }
}

// ---------------- final: out = relu(scale2 * max_k(y2) + shift2) -------------
__global__ __launch_bounds__(256) void kout(const float* __restrict__ m,
                                            const float* __restrict__ st2,
                                            float* __restrict__ out) {
  const int e4 = blockIdx.x * 256 + threadIdx.x;  // 524288 float4s
  const int o0 = (e4 & 31) * 4;
  const float4 v = ((const float4*)m)[e4];
  const float4 sc = *(const float4*)&st2[o0];
  const float4 sh = *(const float4*)&st2[128 + o0];
  float4 r;
  r.x = fmaxf(0.f, fmaf(v.x, sc.x, sh.x));
  r.y = fmaxf(0.f, fmaf(v.y, sc.y, sh.y));
  r.z = fmaxf(0.f, fmaf(v.z, sc.z, sh.z));
  r.w = fmaxf(0.f, fmaf(v.w, sc.w, sh.w));
  ((float4*)out)[e4] = r;
}

extern "C" void kernel_launch(void* const* d_in, const int* in_sizes, int n_in,
                              void* d_out, int out_size, void* d_ws, size_t ws_size,
                              hipStream_t stream) {
  (void)in_sizes; (void)n_in; (void)out_size; (void)ws_size;
  const float* x    = (const float*)d_in[0];
  const float* coor = (const float*)d_in[1];
  const int*   indx = (const int*)d_in[2];
  const float* w1   = (const float*)d_in[3];
  const float* b1   = (const float*)d_in[4];
  const float* g1   = (const float*)d_in[5];
  const float* be1  = (const float*)d_in[6];
  const float* w2   = (const float*)d_in[7];
  const float* b2   = (const float*)d_in[8];
  const float* g2   = (const float*)d_in[9];
  const float* be2  = (const float*)d_in[10];
  float* out = (float*)d_out;

  char* ws = (char*)d_ws;
  int*   knn   = (int*)(ws + 0);
  float* mbuf  = (float*)(ws + 2097152);
  float* part1 = (float*)(ws + 10485760);
  float* part2 = (float*)(ws + 12582912);
  float* wt1   = (float*)(ws + 14680064);
  float* wt2   = (float*)(ws + 14745600);
  float* st1   = (float*)(ws + 14811136);
  float* st2   = (float*)(ws + 14812160);

  float* outc = out + 2097152;   // sampled_coor region of d_out

  kprep<<<320, 256, 0, stream>>>(w1, w2, coor, indx, wt1, wt2, outc);
  kknn<<<16384, 64, 0, stream>>>(coor, indx, knn);
  kphase<1><<<2048, 256, 0, stream>>>(x, indx, knn, wt1, b1, wt2, b2, nullptr, part1, nullptr);
  kreduce<<<1, 1024, 0, stream>>>(part1, g1, be1, st1);
  kphase<2><<<2048, 256, 0, stream>>>(x, indx, knn, wt1, b1, wt2, b2, st1, part2, mbuf);
  kreduce<<<1, 1024, 0, stream>>>(part2, g2, be2, st2);
  kout<<<2048, 256, 0, stream>>>(mbuf, st2, out);
}

// Round 3
// 1277.229 us; speedup vs baseline: 2.7505x; 1.1308x over previous
//
#include <hip/hip_runtime.h>
#include <stdint.h>

// sample_and_group: B=8 N=8192 C=64 S=2048 K=32 OUT=128
// out = (out[8,2048,128], sampled_coor[8,2048,3]) concatenated in d_out (float32).
//
// R2 fix: kknn was insertion-chain-bound (16-deep u64 chain ran every iteration at
// wave granularity; VALUBusy 82%, 7.3M LDS bank conflicts, occupancy 44% from
// 64-thread blocks). New kknn: one query per 256-thread block, per-thread top-8
// (stream of 32), conflict-free column-major LDS candidate dump, wave-0 merge
// (per-lane top-12, conflict-free) + shfl extract-min. coor repacked to float4
// in kprep (coalesced), aliased over part1 region (disjoint lifetime).
//
// Workspace layout (bytes), total ~14.2 MB:
//   [0,2MB)        knn indices  int32[16384*32]
//   [2MB,10MB)     m = max_k y2 f32[16384*128]
//   [10MB,11MB)    coor4 float4[8*8192]   (ALIASES part1; kknn-only lifetime)
//   [10MB,12MB)    partials1    f32[2048*256]  (written by phase1 after kknn)
//   [12MB,14MB)    partials2    f32[2048*256]
//   [14MB,+64KB)   wt1 (w1 transposed, [i][o])
//   [.. ,+64KB)    wt2
//   [.. ,+1KB)     stats1 (scale[128], shift[128])
//   [.. ,+1KB)     stats2

#define N_    8192
#define GPB_  8       // groups per block in phase kernels

__device__ __forceinline__ float f4e(const float4 v, int j) {
  return j == 0 ? v.x : j == 1 ? v.y : j == 2 ? v.z : v.w;
}

// ---------------- prep: weight transpose + coor4 pack + sampled_coor ----------
__global__ __launch_bounds__(256) void kprep(const float* __restrict__ w1,
                                             const float* __restrict__ w2,
                                             const float* __restrict__ coor,
                                             const int* __restrict__ indx,
                                             float* __restrict__ wt1,
                                             float* __restrict__ wt2,
                                             float* __restrict__ outc,
                                             float4* __restrict__ coor4) {
  int e = blockIdx.x * 256 + threadIdx.x;   // grid is exactly 576*256 = 147456
  if (e < 16384) {
    int i = e >> 7, o = e & 127;
    wt1[e] = w1[o * 128 + i];
  } else if (e < 32768) {
    int e2 = e - 16384;
    int i = e2 >> 7, o = e2 & 127;
    wt2[e2] = w2[o * 128 + i];
  } else if (e < 81920) {
    int e2 = e - 32768;                      // 0..49151
    int bs = e2 / 3, c = e2 - bs * 3;
    int b = bs >> 11, s = bs & 2047;
    outc[e2] = coor[(b * N_ + indx[s]) * 3 + c];
  } else {
    int p = e - 81920;                       // 0..65535
    const float* src = coor + (size_t)p * 3;
    coor4[p] = make_float4(src[0], src[1], src[2], 0.f);
  }
}

// ---------------- KNN: one query per 256-thread block -------------------------
// Key = (dist_bits << 32) | point_idx : min-order == (dist asc, idx asc), exactly
// matching stable top_k(-dist). dist via __f*_rn (no FMA contraction) ->
// bit-identical to numpy ((dx*dx+dy*dy)+dz*dz).
// Per-thread top-8 of a 32-item stream; wave-0 merge with per-lane top-12.
// Capacity-overflow probability (fixed input): ~2.5e-8 (thread) / ~6e-10 (merge).
__global__ __launch_bounds__(256) void kknn(const float4* __restrict__ coor4,
                                            const int* __restrict__ indx,
                                            int* __restrict__ knn) {
  __shared__ unsigned long long cand[8 * 256];   // [j][tid] column-major, 16KB
  __shared__ unsigned long long m2[12 * 64];     // [j][lane] column-major, 6KB
  const int gid = blockIdx.x;
  const int b = gid >> 11, s = gid & 2047;
  const int tid = threadIdx.x;
  const float4* cb = coor4 + ((size_t)b << 13);
  const int qi = indx[s];
  const float4 q = cb[qi];

  unsigned long long kb[8];
#pragma unroll
  for (int j = 0; j < 8; ++j) kb[j] = ~0ULL;

  for (int it = 0; it < 32; ++it) {
    const int p = tid + (it << 8);
    const float4 c = cb[p];
    const float dx = __fsub_rn(c.x, q.x);
    const float dy = __fsub_rn(c.y, q.y);
    const float dz = __fsub_rn(c.z, q.z);
    const float dist =
        __fadd_rn(__fadd_rn(__fmul_rn(dx, dx), __fmul_rn(dy, dy)), __fmul_rn(dz, dz));
    unsigned long long key =
        ((unsigned long long)__float_as_uint(dist) << 32) | (unsigned int)p;
    if (key < kb[7]) {                       // sorted insertion, 8-deep
#pragma unroll
      for (int j = 0; j < 8; ++j) {
        const unsigned long long lo = key < kb[j] ? key : kb[j];
        const unsigned long long hi = key < kb[j] ? kb[j] : key;
        kb[j] = lo;
        key = hi;
      }
    }
  }
#pragma unroll
  for (int j = 0; j < 8; ++j) cand[j * 256 + tid] = kb[j];
  __syncthreads();

  if (tid < 64) {
    const int lane = tid;
    // merge: lane L consumes buckets tid = L + 64*w (conflict-free LDS reads)
    unsigned long long mb[12];
#pragma unroll
    for (int j = 0; j < 12; ++j) mb[j] = ~0ULL;
    for (int w = 0; w < 4; ++w) {
#pragma unroll
      for (int j = 0; j < 8; ++j) {
        unsigned long long key = cand[j * 256 + (w << 6) + lane];
        if (key < mb[11]) {
#pragma unroll
          for (int t = 0; t < 12; ++t) {
            const unsigned long long lo = key < mb[t] ? key : mb[t];
            const unsigned long long hi = key < mb[t] ? mb[t] : key;
            mb[t] = lo;
            key = hi;
          }
        }
      }
    }
#pragma unroll
    for (int j = 0; j < 12; ++j) m2[j * 64 + lane] = mb[j];

    // 32x extract-min across the wave's 64 sorted 12-lists
    unsigned long long cur = mb[0];
    int ptr = 1;
    unsigned int myidx = 0;
    for (int r = 0; r < 32; ++r) {
      unsigned long long red = cur;
#pragma unroll
      for (int off = 32; off > 0; off >>= 1) {
        const unsigned long long other = __shfl_xor(red, off, 64);
        red = other < red ? other : red;
      }
      if (lane == r) myidx = (unsigned int)red;
      const unsigned long long ball = __ballot(cur == red);  // unique keys -> 1 lane
      const int src = (int)__builtin_ctzll(ball);
      if (lane == src) {
        cur = (ptr < 12) ? m2[ptr * 64 + lane] : ~0ULL;
        ++ptr;
      }
    }
    if (lane < 32) knn[gid * 32 + lane] = (int)myidx;
  }
}

// ---------------- phase kernels: per-group fused GEMMs -----------------------
// feat[k] = [sx, d_k] with sx row-constant => y1[k][o] = base[o] + sum_i d_k[i]*wt1[64+i][o]
template <int PHASE>
__global__ __launch_bounds__(256, 4) void kphase(
    const float* __restrict__ x, const int* __restrict__ indx,
    const int* __restrict__ knn, const float* __restrict__ wt1,
    const float* __restrict__ b1, const float* __restrict__ wt2,
    const float* __restrict__ b2, const float* __restrict__ st1,
    float* __restrict__ part, float* __restrict__ mout) {
  __shared__ __align__(16) float sx[64];
  __shared__ int nbi[32];
  __shared__ __align__(16) float dls[32 * 64];
  __shared__ __align__(16) float h1ls[PHASE == 2 ? 32 * 128 : 4];
  __shared__ __align__(16) float red[8 * 128];

  const int tid = threadIdx.x;
  const int otile = tid & 31, rtile = tid >> 5;   // 32 x 8 thread tiles
  const int o0 = otile * 4, r0 = rtile * 4;       // 4x4 register tile each
  const int bo = tid & 127, bh = tid >> 7;        // base-dot split: channel, half

  float4* const dls4 = (float4*)dls;

  float sAcc[4] = {0.f, 0.f, 0.f, 0.f};
  float ssAcc[4] = {0.f, 0.f, 0.f, 0.f};
  float s1v[4], t1v[4], b2v[4];
  if constexpr (PHASE == 2) {
#pragma unroll
    for (int j = 0; j < 4; ++j) {
      s1v[j] = st1[o0 + j];
      t1v[j] = st1[128 + o0 + j];
      b2v[j] = b2[o0 + j];
    }
  }
  (void)b2; (void)st1; (void)mout; (void)wt2;
  const float b1v = (bh == 0) ? b1[bo] : 0.f;

#pragma unroll 1
  for (int g = 0; g < GPB_; ++g) {
    const int gid = blockIdx.x * GPB_ + g;
    const int b = gid >> 11, s = gid & 2047;
    const float* xb = x + (size_t)b * (N_ * 64);
    __syncthreads();                              // protect LDS reuse
    if (tid < 64) sx[tid] = xb[indx[s] * 64 + tid];
    if (tid >= 64 && tid < 96) nbi[tid - 64] = knn[gid * 32 + (tid - 64)];
    __syncthreads();
    // stage d = knn_x - sx as float4 (coalesced 16B/lane, 4 rows per wave)
#pragma unroll
    for (int j = 0; j < 2; ++j) {
      const int e4 = tid + 256 * j;               // 0..511 float4s
      const int row = e4 >> 4, col4 = e4 & 15;
      const float4 xv = *(const float4*)&xb[(size_t)nbi[row] * 64 + col4 * 4];
      const float4 sv = ((const float4*)sx)[col4];
      float4 dv;
      dv.x = xv.x - sv.x; dv.y = xv.y - sv.y; dv.z = xv.z - sv.z; dv.w = xv.w - sv.w;
      dls4[row * 16 + col4] = dv;
    }
    // base half-dots: thread -> channel bo, i-range [bh*32, bh*32+32)
    {
      float a = b1v;
#pragma unroll 8
      for (int i = 0; i < 32; ++i) {
        const int ii = bh * 32 + i;
        a = fmaf(sx[ii], wt1[ii * 128 + bo], a);
      }
      red[tid] = a;                               // rows 0..1 of red
    }
    __syncthreads();

    float acc[4][4];
    {
      const float4 blo = *(const float4*)&red[o0];
      const float4 bhi = *(const float4*)&red[128 + o0];
#pragma unroll
      for (int rr = 0; rr < 4; ++rr) {
        acc[rr][0] = blo.x + bhi.x; acc[rr][1] = blo.y + bhi.y;
        acc[rr][2] = blo.z + bhi.z; acc[rr][3] = blo.w + bhi.w;
      }
    }
#pragma unroll 2
    for (int i = 0; i < 64; i += 4) {             // layer-1 GEMM (K=64)
      float4 dv[4], wv[4];
#pragma unroll
      for (int rr = 0; rr < 4; ++rr) dv[rr] = dls4[(r0 + rr) * 16 + (i >> 2)];
#pragma unroll
      for (int ii = 0; ii < 4; ++ii) wv[ii] = *(const float4*)&wt1[(64 + i + ii) * 128 + o0];
#pragma unroll
      for (int ii = 0; ii < 4; ++ii)
#pragma unroll
        for (int rr = 0; rr < 4; ++rr) {
          const float dval = f4e(dv[rr], ii);
          acc[rr][0] = fmaf(dval, wv[ii].x, acc[rr][0]);
          acc[rr][1] = fmaf(dval, wv[ii].y, acc[rr][1]);
          acc[rr][2] = fmaf(dval, wv[ii].z, acc[rr][2]);
          acc[rr][3] = fmaf(dval, wv[ii].w, acc[rr][3]);
        }
    }

    if constexpr (PHASE == 1) {
#pragma unroll
      for (int jj = 0; jj < 4; ++jj)
#pragma unroll
        for (int rr = 0; rr < 4; ++rr) {
          const float v = acc[rr][jj];
          sAcc[jj] += v;
          ssAcc[jj] = fmaf(v, v, ssAcc[jj]);
        }
    } else {
      // bn1 + relu -> h1 in LDS
#pragma unroll
      for (int rr = 0; rr < 4; ++rr) {
        float4 hv;
        hv.x = fmaxf(0.f, fmaf(acc[rr][0], s1v[0], t1v[0]));
        hv.y = fmaxf(0.f, fmaf(acc[rr][1], s1v[1], t1v[1]));
        hv.z = fmaxf(0.f, fmaf(acc[rr][2], s1v[2], t1v[2]));
        hv.w = fmaxf(0.f, fmaf(acc[rr][3], s1v[3], t1v[3]));
        *(float4*)&h1ls[(r0 + rr) * 128 + o0] = hv;
      }
      __syncthreads();
      float acc2[4][4];
#pragma unroll
      for (int rr = 0; rr < 4; ++rr) {
        acc2[rr][0] = b2v[0]; acc2[rr][1] = b2v[1];
        acc2[rr][2] = b2v[2]; acc2[rr][3] = b2v[3];
      }
#pragma unroll 2
      for (int i = 0; i < 128; i += 4) {          // layer-2 GEMM (K=128)
        float4 hv[4], wv[4];
#pragma unroll
        for (int rr = 0; rr < 4; ++rr) hv[rr] = *(const float4*)&h1ls[(r0 + rr) * 128 + i];
#pragma unroll
        for (int ii = 0; ii < 4; ++ii) wv[ii] = *(const float4*)&wt2[(i + ii) * 128 + o0];
#pragma unroll
        for (int ii = 0; ii < 4; ++ii)
#pragma unroll
          for (int rr = 0; rr < 4; ++rr) {
            const float hval = f4e(hv[rr], ii);
            acc2[rr][0] = fmaf(hval, wv[ii].x, acc2[rr][0]);
            acc2[rr][1] = fmaf(hval, wv[ii].y, acc2[rr][1]);
            acc2[rr][2] = fmaf(hval, wv[ii].z, acc2[rr][2]);
            acc2[rr][3] = fmaf(hval, wv[ii].w, acc2[rr][3]);
          }
      }
#pragma unroll
      for (int jj = 0; jj < 4; ++jj)              // stats of y2 (pre-BN2)
#pragma unroll
        for (int rr = 0; rr < 4; ++rr) {
          const float v = acc2[rr][jj];
          sAcc[jj] += v;
          ssAcc[jj] = fmaf(v, v, ssAcc[jj]);
        }
      float4 mv;                                  // per-group max over k rows
      mv.x = fmaxf(fmaxf(acc2[0][0], acc2[1][0]), fmaxf(acc2[2][0], acc2[3][0]));
      mv.y = fmaxf(fmaxf(acc2[0][1], acc2[1][1]), fmaxf(acc2[2][1], acc2[3][1]));
      mv.z = fmaxf(fmaxf(acc2[0][2], acc2[1][2]), fmaxf(acc2[2][2], acc2[3][2]));
      mv.w = fmaxf(fmaxf(acc2[0][3], acc2[1][3]), fmaxf(acc2[2][3], acc2[3][3]));
      *(float4*)&red[rtile * 128 + o0] = mv;
      __syncthreads();
      if (tid < 128) {
        float mm = red[tid];
#pragma unroll
        for (int rt = 1; rt < 8; ++rt) mm = fmaxf(mm, red[rt * 128 + tid]);
        mout[(size_t)gid * 128 + tid] = mm;
      }
    }
  }

  // block-level channel reduction of sums -> partials
  __syncthreads();
  *(float4*)&red[rtile * 128 + o0] = make_float4(sAcc[0], sAcc[1], sAcc[2], sAcc[3]);
  __syncthreads();
  if (tid < 128) {
    float t = red[tid];
#pragma unroll
    for (int rt = 1; rt < 8; ++rt) t += red[rt * 128 + tid];
    part[blockIdx.x * 256 + tid] = t;
  }
  __syncthreads();
  *(float4*)&red[rtile * 128 + o0] = make_float4(ssAcc[0], ssAcc[1], ssAcc[2], ssAcc[3]);
  __syncthreads();
  if (tid < 128) {
    float t = red[tid];
#pragma unroll
    for (int rt = 1; rt < 8; ++rt) t += red[rt * 128 + tid];
    part[blockIdx.x * 256 + 128 + tid] = t;
  }
}

// ---------------- stats finalize (double precision) --------------------------
__global__ __launch_bounds__(1024) void kreduce(const float* __restrict__ part,
                                                const float* __restrict__ gam,
                                                const float* __restrict__ bet,
                                                float* __restrict__ st) {
  __shared__ double redd[4][256];
  const int tid = threadIdx.x;
  const int c = tid & 255, pq = tid >> 8;
  double acc = 0.0;
  for (int row = pq; row < 2048; row += 4) acc += (double)part[row * 256 + c];
  redd[pq][c] = acc;
  __syncthreads();
  if (tid < 256) redd[0][tid] = redd[0][tid] + redd[1][tid] + redd[2][tid] + redd[3][tid];
  __syncthreads();
  if (tid < 128) {
    const double Sv = redd[0][tid], SSv = redd[0][128 + tid];
    const double cnt = 524288.0;                 // B*S*K
    const double mean = Sv / cnt;
    const double var = SSv / cnt - mean * mean;
    const double scale = (double)gam[tid] / sqrt(var + 1e-5);
    st[tid] = (float)scale;
    st[128 + tid] = (float)((double)bet[tid] - mean * scale);
  }
}

// ---------------- final: out = relu(scale2 * max_k(y2) + shift2) -------------
__global__ __launch_bounds__(256) void kout(const float* __restrict__ m,
                                            const float* __restrict__ st2,
                                            float* __restrict__ out) {
  const int e4 = blockIdx.x * 256 + threadIdx.x;  // 524288 float4s
  const int o0 = (e4 & 31) * 4;
  const float4 v = ((const float4*)m)[e4];
  const float4 sc = *(const float4*)&st2[o0];
  const float4 sh = *(const float4*)&st2[128 + o0];
  float4 r;
  r.x = fmaxf(0.f, fmaf(v.x, sc.x, sh.x));
  r.y = fmaxf(0.f, fmaf(v.y, sc.y, sh.y));
  r.z = fmaxf(0.f, fmaf(v.z, sc.z, sh.z));
  r.w = fmaxf(0.f, fmaf(v.w, sc.w, sh.w));
  ((float4*)out)[e4] = r;
}

extern "C" void kernel_launch(void* const* d_in, const int* in_sizes, int n_in,
                              void* d_out, int out_size, void* d_ws, size_t ws_size,
                              hipStream_t stream) {
  (void)in_sizes; (void)n_in; (void)out_size; (void)ws_size;
  const float* x    = (const float*)d_in[0];
  const float* coor = (const float*)d_in[1];
  const int*   indx = (const int*)d_in[2];
  const float* w1   = (const float*)d_in[3];
  const float* b1   = (const float*)d_in[4];
  const float* g1   = (const float*)d_in[5];
  const float* be1  = (const float*)d_in[6];
  const float* w2   = (const float*)d_in[7];
  const float* b2   = (const float*)d_in[8];
  const float* g2   = (const float*)d_in[9];
  const float* be2  = (const float*)d_in[10];
  float* out = (float*)d_out;

  char* ws = (char*)d_ws;
  int*    knn   = (int*)(ws + 0);
  float*  mbuf  = (float*)(ws + 2097152);
  float*  part1 = (float*)(ws + 10485760);
  float4* coor4 = (float4*)(ws + 10485760);  // aliases part1: kknn-only lifetime
  float*  part2 = (float*)(ws + 12582912);
  float*  wt1   = (float*)(ws + 14680064);
  float*  wt2   = (float*)(ws + 14745600);
  float*  st1   = (float*)(ws + 14811136);
  float*  st2   = (float*)(ws + 14812160);

  float* outc = out + 2097152;   // sampled_coor region of d_out

  kprep<<<576, 256, 0, stream>>>(w1, w2, coor, indx, wt1, wt2, outc, coor4);
  kknn<<<16384, 256, 0, stream>>>(coor4, indx, knn);
  kphase<1><<<2048, 256, 0, stream>>>(x, indx, knn, wt1, b1, wt2, b2, nullptr, part1, nullptr);
  kreduce<<<1, 1024, 0, stream>>>(part1, g1, be1, st1);
  kphase<2><<<2048, 256, 0, stream>>>(x, indx, knn, wt1, b1, wt2, b2, st1, part2, mbuf);
  kreduce<<<1, 1024, 0, stream>>>(part2, g2, be2, st2);
  kout<<<2048, 256, 0, stream>>>(mbuf, st2, out);
}

// Round 4
// 939.275 us; speedup vs baseline: 3.7401x; 1.3598x over previous
//
#include <hip/hip_runtime.h>
#include <stdint.h>

// sample_and_group: B=8 N=8192 C=64 S=2048 K=32 OUT=128
// out = (out[8,2048,128], sampled_coor[8,2048,3]) concatenated in d_out (float32).
//
// R3 fix: phases were fp32-VALU GEMMs (MfmaUtil 0, VALUBusy 50%, 481 us).
// Rewritten on v_mfma_f32_32x32x16_bf16: wave = 32-col tile, M=32 neighbors.
// B-frags (weights, bf16 [o][k] = native w row layout) + BN consts preloaded in
// registers; A1 = (x[nb]-sx) packed bf16 in-register; base = b1 + sx.w1_lo kept
// exact fp32 and folded into acc init (C-layout col is per-lane constant);
// stats/max read C-layout natively (1 shfl, channel owned by one wave);
// phase2 h1 goes C-layout -> LDS (row-major, +8 bf16 pad) -> A-frags.
//
// Workspace layout (bytes):
//   [0,2MB)        knn indices  int32[16384*32]
//   [2MB,10MB)     m = max_k y2 f32[16384*128]
//   [10MB,11MB)    coor4 float4[8*8192]   (ALIASES part1; kknn-only lifetime)
//   [10MB,12MB)    partials1    f32[2048*256]
//   [12MB,14MB)    partials2    f32[2048*256]
//   [14MB,+32KB)   wt1lo fp32 [i=0..63][o]   (base dot, transposed)
//   [..,+16KB)     w1bh  bf16 [o][i=0..63]   (hi half of w1)
//   [..,+32KB)     w2b   bf16 [o][k=0..127]
//   [..,+1KB)      stats1 (scale[128], shift[128])
//   [..,+1KB)      stats2

#define N_    8192
#define GPB_  8       // groups per block in phase kernels

typedef __attribute__((ext_vector_type(8))) short bf8;
typedef __attribute__((ext_vector_type(16))) float f32x16;

__device__ __forceinline__ unsigned int bf1u(float f) {   // RNE fp32->bf16 bits
  unsigned int u = __float_as_uint(f);
  return (u + 0x7fffu + ((u >> 16) & 1u)) >> 16;
}
__device__ __forceinline__ unsigned int bfpair(float lo, float hi) {
  return bf1u(lo) | (bf1u(hi) << 16);
}

// ---------------- prep: weight layouts + coor4 pack + sampled_coor ------------
__global__ __launch_bounds__(256) void kprep(const float* __restrict__ w1,
                                             const float* __restrict__ w2,
                                             const float* __restrict__ coor,
                                             const int* __restrict__ indx,
                                             float* __restrict__ wt1lo,
                                             unsigned short* __restrict__ w1bh,
                                             unsigned short* __restrict__ w2b,
                                             float* __restrict__ outc,
                                             float4* __restrict__ coor4) {
  int e = blockIdx.x * 256 + threadIdx.x;   // grid is exactly 576*256 = 147456
  if (e < 8192) {                            // wt1lo[i][o] = w1[o][i], i<64
    int i = e >> 7, o = e & 127;
    wt1lo[e] = w1[o * 128 + i];
  } else if (e < 16384) {                    // w1bh[o][i] = bf16(w1[o][64+i])
    int e2 = e - 8192;
    int o = e2 >> 6, i = e2 & 63;
    w1bh[e2] = (unsigned short)bf1u(w1[o * 128 + 64 + i]);
  } else if (e < 32768) {                    // w2b[o][k] = bf16(w2[o][k])
    int e2 = e - 16384;
    w2b[e2] = (unsigned short)bf1u(w2[e2]);
  } else if (e < 81920) {
    int e2 = e - 32768;                      // 0..49151 sampled_coor
    int bs = e2 / 3, c = e2 - bs * 3;
    int b = bs >> 11, s = bs & 2047;
    outc[e2] = coor[(b * N_ + indx[s]) * 3 + c];
  } else {
    int p = e - 81920;                       // 0..65535 coor4 pack
    const float* src = coor + (size_t)p * 3;
    coor4[p] = make_float4(src[0], src[1], src[2], 0.f);
  }
}

// ---------------- KNN: one query per 256-thread block -------------------------
// Key = (dist_bits << 32) | point_idx : min-order == (dist asc, idx asc) ==
// stable top_k(-dist). dist via __f*_rn -> bit-identical to numpy.
__global__ __launch_bounds__(256) void kknn(const float4* __restrict__ coor4,
                                            const int* __restrict__ indx,
                                            int* __restrict__ knn) {
  __shared__ unsigned long long cand[8 * 256];   // [j][tid] column-major
  __shared__ unsigned long long m2[12 * 64];     // [j][lane] column-major
  const int gid = blockIdx.x;
  const int b = gid >> 11, s = gid & 2047;
  const int tid = threadIdx.x;
  const float4* cb = coor4 + ((size_t)b << 13);
  const int qi = indx[s];
  const float4 q = cb[qi];

  unsigned long long kb[8];
#pragma unroll
  for (int j = 0; j < 8; ++j) kb[j] = ~0ULL;

  for (int it = 0; it < 32; ++it) {
    const int p = tid + (it << 8);
    const float4 c = cb[p];
    const float dx = __fsub_rn(c.x, q.x);
    const float dy = __fsub_rn(c.y, q.y);
    const float dz = __fsub_rn(c.z, q.z);
    const float dist =
        __fadd_rn(__fadd_rn(__fmul_rn(dx, dx), __fmul_rn(dy, dy)), __fmul_rn(dz, dz));
    unsigned long long key =
        ((unsigned long long)__float_as_uint(dist) << 32) | (unsigned int)p;
    if (key < kb[7]) {
#pragma unroll
      for (int j = 0; j < 8; ++j) {
        const unsigned long long lo = key < kb[j] ? key : kb[j];
        const unsigned long long hi = key < kb[j] ? kb[j] : key;
        kb[j] = lo;
        key = hi;
      }
    }
  }
#pragma unroll
  for (int j = 0; j < 8; ++j) cand[j * 256 + tid] = kb[j];
  __syncthreads();

  if (tid < 64) {
    const int lane = tid;
    unsigned long long mb[12];
#pragma unroll
    for (int j = 0; j < 12; ++j) mb[j] = ~0ULL;
    for (int w = 0; w < 4; ++w) {
#pragma unroll
      for (int j = 0; j < 8; ++j) {
        unsigned long long key = cand[j * 256 + (w << 6) + lane];
        if (key < mb[11]) {
#pragma unroll
          for (int t = 0; t < 12; ++t) {
            const unsigned long long lo = key < mb[t] ? key : mb[t];
            const unsigned long long hi = key < mb[t] ? mb[t] : key;
            mb[t] = lo;
            key = hi;
          }
        }
      }
    }
#pragma unroll
    for (int j = 0; j < 12; ++j) m2[j * 64 + lane] = mb[j];

    unsigned long long cur = mb[0];
    int ptr = 1;
    unsigned int myidx = 0;
    for (int r = 0; r < 32; ++r) {
      unsigned long long red = cur;
#pragma unroll
      for (int off = 32; off > 0; off >>= 1) {
        const unsigned long long other = __shfl_xor(red, off, 64);
        red = other < red ? other : red;
      }
      if (lane == r) myidx = (unsigned int)red;
      const unsigned long long ball = __ballot(cur == red);
      const int src = (int)__builtin_ctzll(ball);
      if (lane == src) {
        cur = (ptr < 12) ? m2[ptr * 64 + lane] : ~0ULL;
        ++ptr;
      }
    }
    if (lane < 32) knn[gid * 32 + lane] = (int)myidx;
  }
}

// ---------------- phase kernels: MFMA fused GEMMs ----------------------------
// Wave w owns cols 32w..32w+31. Per lane: m = lane&31 (A row / D col), q2 = lane>>5.
// A layout: A[m=lane&31][k=q2*8+j]; B layout: B^T[n=lane&31][k=q2*8+j];
// C/D layout: col=lane&31, row=(reg&3)+8*(reg>>2)+4*q2  [m74/m101-verified].
template <int PHASE>
__global__ __launch_bounds__(256, 4) void kphase(
    const float* __restrict__ x, const int* __restrict__ indx,
    const int* __restrict__ knn, const float* __restrict__ wt1lo,
    const float* __restrict__ b1, const unsigned short* __restrict__ w1bh,
    const unsigned short* __restrict__ w2b, const float* __restrict__ b2,
    const float* __restrict__ st1, float* __restrict__ part,
    float* __restrict__ mout) {
  __shared__ __align__(16) float sx[64];
  __shared__ int nbi[32];
  __shared__ float red[256];
  __shared__ __align__(16) unsigned short h1[PHASE == 2 ? 32 * 136 : 8];

  const int tid = threadIdx.x;
  const int w = tid >> 6;
  const int lane = tid & 63;
  const int m = lane & 31, q2 = lane >> 5;
  const int col = (w << 5) + m;              // output channel of this lane
  const int bo = tid & 127, bh = tid >> 7;   // base-dot mapping

  // group-invariant operands in registers
  bf8 bf1[4];
#pragma unroll
  for (int t = 0; t < 4; ++t)
    bf1[t] = *(const bf8*)&w1bh[col * 64 + t * 16 + q2 * 8];
  bf8 bf2[8];
  float s1 = 0.f, t1 = 0.f, b2v = 0.f;
  if constexpr (PHASE == 2) {
#pragma unroll
    for (int t = 0; t < 8; ++t)
      bf2[t] = *(const bf8*)&w2b[col * 128 + t * 16 + q2 * 8];
    s1 = st1[col];
    t1 = st1[128 + col];
    b2v = b2[col];
  }
  (void)w2b; (void)b2; (void)st1; (void)mout;
  const float b1v = (bh == 0) ? b1[bo] : 0.f;

  float sum = 0.f, ssq = 0.f;

#pragma unroll 1
  for (int g = 0; g < GPB_; ++g) {
    const int gid = blockIdx.x * GPB_ + g;
    const int b = gid >> 11, s = gid & 2047;
    const float* xb = x + (size_t)b * (N_ * 64);
    __syncthreads();                         // LDS reuse guard
    if (tid < 64) sx[tid] = xb[(size_t)indx[s] * 64 + tid];
    if (tid >= 64 && tid < 96) nbi[tid - 64] = knn[gid * 32 + (tid - 64)];
    __syncthreads();

    // exact fp32 base half-dots: base[o] = b1[o] + sx . w1[o][0:64]
    float a = b1v;
#pragma unroll 8
    for (int i = 0; i < 32; ++i) {
      const int ii = (bh << 5) + i;
      a = fmaf(sx[ii], wt1lo[ii * 128 + bo], a);
    }
    red[tid] = a;

    // A1 frags: d = x[nb[m]] - sx, bf16, in-register
    const float* xr = xb + (size_t)nbi[m] * 64;
    bf8 af[4];
#pragma unroll
    for (int t = 0; t < 4; ++t) {
      const int k0 = t * 16 + q2 * 8;
      const float4 xa = *(const float4*)(xr + k0);
      const float4 xc = *(const float4*)(xr + k0 + 4);
      const float4 sa = *(const float4*)(sx + k0);
      const float4 sc = *(const float4*)(sx + k0 + 4);
      union { bf8 v; unsigned int u[4]; } uu;
      uu.u[0] = bfpair(xa.x - sa.x, xa.y - sa.y);
      uu.u[1] = bfpair(xa.z - sa.z, xa.w - sa.w);
      uu.u[2] = bfpair(xc.x - sc.x, xc.y - sc.y);
      uu.u[3] = bfpair(xc.z - sc.z, xc.w - sc.w);
      af[t] = uu.v;
    }
    __syncthreads();                         // red ready

    const float bb = red[col] + red[128 + col];
    f32x16 acc;
#pragma unroll
    for (int r = 0; r < 16; ++r) acc[r] = bb;
#pragma unroll
    for (int t = 0; t < 4; ++t)
      acc = __builtin_amdgcn_mfma_f32_32x32x16_bf16(af[t], bf1[t], acc, 0, 0, 0);

    if constexpr (PHASE == 1) {
#pragma unroll
      for (int r = 0; r < 16; ++r) {
        const float v = acc[r];
        sum += v;
        ssq = fmaf(v, v, ssq);
      }
    } else {
      // bn1 + relu -> h1 bf16 in LDS (C-layout scatter, row stride 136)
#pragma unroll
      for (int r = 0; r < 16; ++r) {
        const float hv = fmaxf(0.f, fmaf(acc[r], s1, t1));
        const int row = (r & 3) + ((r >> 2) << 3) + (q2 << 2);
        h1[row * 136 + col] = (unsigned short)bf1u(hv);
      }
      __syncthreads();                       // h1 ready

      f32x16 acc2;
#pragma unroll
      for (int r = 0; r < 16; ++r) acc2[r] = b2v;
#pragma unroll
      for (int t = 0; t < 8; ++t) {
        const bf8 a2 = *(const bf8*)&h1[m * 136 + t * 16 + q2 * 8];
        acc2 = __builtin_amdgcn_mfma_f32_32x32x16_bf16(a2, bf2[t], acc2, 0, 0, 0);
      }

      float mx = -1e30f;
#pragma unroll
      for (int r = 0; r < 16; ++r) {
        const float v = acc2[r];
        sum += v;
        ssq = fmaf(v, v, ssq);
        mx = fmaxf(mx, v);
      }
      mx = fmaxf(mx, __shfl_xor(mx, 32, 64));
      if (lane < 32) mout[(size_t)gid * 128 + col] = mx;
    }
  }

  // channel partials: each channel owned by exactly one wave
  sum += __shfl_xor(sum, 32, 64);
  ssq += __shfl_xor(ssq, 32, 64);
  if (lane < 32) {
    part[blockIdx.x * 256 + col] = sum;
    part[blockIdx.x * 256 + 128 + col] = ssq;
  }
}

// ---------------- stats finalize (double precision) --------------------------
__global__ __launch_bounds__(1024) void kreduce(const float* __restrict__ part,
                                                const float* __restrict__ gam,
                                                const float* __restrict__ bet,
                                                float* __restrict__ st) {
  __shared__ double redd[4][256];
  const int tid = threadIdx.x;
  const int c = tid & 255, pq = tid >> 8;
  double acc = 0.0;
  for (int row = pq; row < 2048; row += 4) acc += (double)part[row * 256 + c];
  redd[pq][c] = acc;
  __syncthreads();
  if (tid < 256) redd[0][tid] = redd[0][tid] + redd[1][tid] + redd[2][tid] + redd[3][tid];
  __syncthreads();
  if (tid < 128) {
    const double Sv = redd[0][tid], SSv = redd[0][128 + tid];
    const double cnt = 524288.0;                 // B*S*K
    const double mean = Sv / cnt;
    const double var = SSv / cnt - mean * mean;
    const double scale = (double)gam[tid] / sqrt(var + 1e-5);
    st[tid] = (float)scale;
    st[128 + tid] = (float)((double)bet[tid] - mean * scale);
  }
}

// ---------------- final: out = relu(scale2 * max_k(y2) + shift2) -------------
__global__ __launch_bounds__(256) void kout(const float* __restrict__ m,
                                            const float* __restrict__ st2,
                                            float* __restrict__ out) {
  const int e4 = blockIdx.x * 256 + threadIdx.x;  // 524288 float4s
  const int o0 = (e4 & 31) * 4;
  const float4 v = ((const float4*)m)[e4];
  const float4 sc = *(const float4*)&st2[o0];
  const float4 sh = *(const float4*)&st2[128 + o0];
  float4 r;
  r.x = fmaxf(0.f, fmaf(v.x, sc.x, sh.x));
  r.y = fmaxf(0.f, fmaf(v.y, sc.y, sh.y));
  r.z = fmaxf(0.f, fmaf(v.z, sc.z, sh.z));
  r.w = fmaxf(0.f, fmaf(v.w, sc.w, sh.w));
  ((float4*)out)[e4] = r;
}

extern "C" void kernel_launch(void* const* d_in, const int* in_sizes, int n_in,
                              void* d_out, int out_size, void* d_ws, size_t ws_size,
                              hipStream_t stream) {
  (void)in_sizes; (void)n_in; (void)out_size; (void)ws_size;
  const float* x    = (const float*)d_in[0];
  const float* coor = (const float*)d_in[1];
  const int*   indx = (const int*)d_in[2];
  const float* w1   = (const float*)d_in[3];
  const float* b1   = (const float*)d_in[4];
  const float* g1   = (const float*)d_in[5];
  const float* be1  = (const float*)d_in[6];
  const float* w2   = (const float*)d_in[7];
  const float* b2   = (const float*)d_in[8];
  const float* g2   = (const float*)d_in[9];
  const float* be2  = (const float*)d_in[10];
  float* out = (float*)d_out;

  char* ws = (char*)d_ws;
  int*            knn   = (int*)(ws + 0);
  float*          mbuf  = (float*)(ws + 2097152);
  float*          part1 = (float*)(ws + 10485760);
  float4*         coor4 = (float4*)(ws + 10485760); // aliases part1 (disjoint lifetime)
  float*          part2 = (float*)(ws + 12582912);
  float*          wt1lo = (float*)(ws + 14680064);
  unsigned short* w1bh  = (unsigned short*)(ws + 14712832);
  unsigned short* w2b   = (unsigned short*)(ws + 14729216);
  float*          st1   = (float*)(ws + 14761984);
  float*          st2   = (float*)(ws + 14763008);

  float* outc = out + 2097152;   // sampled_coor region of d_out

  kprep<<<576, 256, 0, stream>>>(w1, w2, coor, indx, wt1lo, w1bh, w2b, outc, coor4);
  kknn<<<16384, 256, 0, stream>>>(coor4, indx, knn);
  kphase<1><<<2048, 256, 0, stream>>>(x, indx, knn, wt1lo, b1, w1bh, w2b, b2, nullptr,
                                      part1, nullptr);
  kreduce<<<1, 1024, 0, stream>>>(part1, g1, be1, st1);
  kphase<2><<<2048, 256, 0, stream>>>(x, indx, knn, wt1lo, b1, w1bh, w2b, b2, st1,
                                      part2, mbuf);
  kreduce<<<1, 1024, 0, stream>>>(part2, g2, be2, st2);
  kout<<<2048, 256, 0, stream>>>(mbuf, st2, out);
}

// Round 5
// 757.354 us; speedup vs baseline: 4.6385x; 1.2402x over previous
//
#include <hip/hip_runtime.h>
#include <stdint.h>

// sample_and_group: B=8 N=8192 C=64 S=2048 K=32 OUT=128
// out = (out[8,2048,128], sampled_coor[8,2048,3]) concatenated in d_out (float32).
//
// R4 fix: kknn was insertion-chain bound (387us, VALUBusy 84%). Since downstream
// (max over K, global mean/var) is permutation-invariant, only the SET of the 32
// smallest (dist,idx) keys matters. New kknn: register-resident dists + exact
// threshold T = 32nd-smallest of 256 thread-mins (provably >= d32 since <=31
// elements lie strictly below d32) -> compact ~40 candidates -> exact bitonic
// top-32 by u64 key. Distances stay bit-exact (__f*_rn chain, (dx*dx+dy*dy)+dz*dz).
//
// Workspace layout (bytes):
//   [0,2MB)        knn indices  int32[16384*32]
//   [2MB,10MB)     m = max_k y2 f32[16384*128]
//   [10MB,11MB)    coor4 float4[8*8192]   (ALIASES part1; kknn-only lifetime)
//   [10MB,12MB)    partials1    f32[2048*256]
//   [12MB,14MB)    partials2    f32[2048*256]
//   [14MB,+32KB)   wt1lo fp32 [i=0..63][o]   (base dot, transposed)
//   [..,+16KB)     w1bh  bf16 [o][i=0..63]   (hi half of w1)
//   [..,+32KB)     w2b   bf16 [o][k=0..127]
//   [..,+1KB)      stats1 (scale[128], shift[128])
//   [..,+1KB)      stats2

#define N_    8192
#define GPB_  8       // groups per block in phase kernels

typedef __attribute__((ext_vector_type(8))) short bf8;
typedef __attribute__((ext_vector_type(16))) float f32x16;

__device__ __forceinline__ unsigned int bf1u(float f) {   // RNE fp32->bf16 bits
  unsigned int u = __float_as_uint(f);
  return (u + 0x7fffu + ((u >> 16) & 1u)) >> 16;
}
__device__ __forceinline__ unsigned int bfpair(float lo, float hi) {
  return bf1u(lo) | (bf1u(hi) << 16);
}

// ---------------- prep: weight layouts + coor4 pack + sampled_coor ------------
__global__ __launch_bounds__(256) void kprep(const float* __restrict__ w1,
                                             const float* __restrict__ w2,
                                             const float* __restrict__ coor,
                                             const int* __restrict__ indx,
                                             float* __restrict__ wt1lo,
                                             unsigned short* __restrict__ w1bh,
                                             unsigned short* __restrict__ w2b,
                                             float* __restrict__ outc,
                                             float4* __restrict__ coor4) {
  int e = blockIdx.x * 256 + threadIdx.x;   // grid is exactly 576*256 = 147456
  if (e < 8192) {                            // wt1lo[i][o] = w1[o][i], i<64
    int i = e >> 7, o = e & 127;
    wt1lo[e] = w1[o * 128 + i];
  } else if (e < 16384) {                    // w1bh[o][i] = bf16(w1[o][64+i])
    int e2 = e - 8192;
    int o = e2 >> 6, i = e2 & 63;
    w1bh[e2] = (unsigned short)bf1u(w1[o * 128 + 64 + i]);
  } else if (e < 32768) {                    // w2b[o][k] = bf16(w2[o][k])
    int e2 = e - 16384;
    w2b[e2] = (unsigned short)bf1u(w2[e2]);
  } else if (e < 81920) {
    int e2 = e - 32768;                      // 0..49151 sampled_coor
    int bs = e2 / 3, c = e2 - bs * 3;
    int b = bs >> 11, s = bs & 2047;
    outc[e2] = coor[(b * N_ + indx[s]) * 3 + c];
  } else {
    int p = e - 81920;                       // 0..65535 coor4 pack
    const float* src = coor + (size_t)p * 3;
    coor4[p] = make_float4(src[0], src[1], src[2], 0.f);
  }
}

// ---------------- KNN: threshold-select, one query per 256-thread block -------
// Output = SET of 32 smallest keys (dist_bits<<32 | idx); order arbitrary
// (downstream max/mean/var are permutation-invariant over K).
__global__ __launch_bounds__(256, 4) void kknn(const float4* __restrict__ coor4,
                                               const int* __restrict__ indx,
                                               int* __restrict__ knn) {
  __shared__ float smin[128];                 // 4 waves x 32 smallest thread-mins
  __shared__ float smrg[64];                  // 2 pairwise-merged 32-lists
  __shared__ float sT;
  __shared__ unsigned long long cands[128];
  __shared__ unsigned long long ssort[128];
  __shared__ int ccnt;

  const int gid = blockIdx.x;
  const int b = gid >> 11, s = gid & 2047;
  const int tid = threadIdx.x;
  const int w = tid >> 6, lane = tid & 63;
  const float4* cb = coor4 + ((size_t)b << 13);
  const float4 q = cb[indx[s]];

  // pass 1: 32 exact distances in registers; track thread-min
  float dist[32];
  float dmin = 3.4e38f;
#pragma unroll
  for (int it = 0; it < 32; ++it) {
    const float4 c = cb[tid + (it << 8)];
    const float dx = __fsub_rn(c.x, q.x);
    const float dy = __fsub_rn(c.y, q.y);
    const float dz = __fsub_rn(c.z, q.z);
    const float d =
        __fadd_rn(__fadd_rn(__fmul_rn(dx, dx), __fmul_rn(dy, dy)), __fmul_rn(dz, dz));
    dist[it] = d;
    dmin = fminf(dmin, d);
  }
  if (tid == 0) ccnt = 0;
  if (tid < 128) cands[tid] = ~0ULL;

  // pass 2: T = exact 32nd smallest of the 256 thread-mins
  float v = dmin;                             // per-wave bitonic sort (ascending)
#pragma unroll
  for (int k = 2; k <= 64; k <<= 1) {
#pragma unroll
    for (int j = k >> 1; j >= 1; j >>= 1) {
      const float o = __shfl_xor(v, j, 64);
      const bool dirAsc = ((lane & k) == 0);
      const bool lower = ((lane & j) == 0);
      const float lo = fminf(v, o), hi = fmaxf(v, o);
      v = (dirAsc == lower) ? lo : hi;
    }
  }
  if (lane < 32) smin[w * 32 + lane] = v;
  __syncthreads();
  if (w < 2) {                                // merge lists (2w, 2w+1) -> 32 smallest
    float a = (lane < 32) ? smin[w * 64 + lane] : smin[w * 64 + 32 + (63 - lane)];
#pragma unroll
    for (int j = 32; j >= 1; j >>= 1) {
      const float o = __shfl_xor(a, j, 64);
      const float lo = fminf(a, o), hi = fmaxf(a, o);
      a = ((lane & j) == 0) ? lo : hi;
    }
    if (lane < 32) smrg[w * 32 + lane] = a;
  }
  __syncthreads();
  if (w == 0) {                               // final merge -> 32nd smallest value
    float a = (lane < 32) ? smrg[lane] : smrg[32 + (63 - lane)];
#pragma unroll
    for (int j = 32; j >= 1; j >>= 1) {
      const float o = __shfl_xor(a, j, 64);
      const float lo = fminf(a, o), hi = fmaxf(a, o);
      a = ((lane & j) == 0) ? lo : hi;
    }
    if (lane == 31) sT = a;
  }
  __syncthreads();
  const float T = sT;

  // pass 3: compact candidates (dist <= T); expected ~34-40, capacity 128
#pragma unroll
  for (int it = 0; it < 32; ++it) {
    if (dist[it] <= T) {
      const int pos = atomicAdd(&ccnt, 1);
      if (pos < 128)
        cands[pos] = ((unsigned long long)__float_as_uint(dist[it]) << 32) |
                     (unsigned int)(tid + (it << 8));
    }
  }
  __syncthreads();

  // pass 4: exact top-32 of <=128 candidates by u64 key
  if (w < 2) {                                // two parallel bitonic sort-64s
    unsigned long long kv = cands[w * 64 + lane];
#pragma unroll
    for (int k = 2; k <= 64; k <<= 1) {
#pragma unroll
      for (int j = k >> 1; j >= 1; j >>= 1) {
        const unsigned long long o = __shfl_xor(kv, j, 64);
        const bool dirAsc = ((lane & k) == 0);
        const bool lower = ((lane & j) == 0);
        const unsigned long long lo = o < kv ? o : kv;
        const unsigned long long hi = o < kv ? kv : o;
        kv = (dirAsc == lower) ? lo : hi;
      }
    }
    ssort[w * 64 + lane] = kv;
  }
  __syncthreads();
  if (w == 0) {                               // reverse-merge; lo-half holds 64 smallest
    const unsigned long long a = ssort[lane];
    const unsigned long long b2 = ssort[64 + 63 - lane];
    unsigned long long m = a < b2 ? a : b2;   // bitonic 64-seq
#pragma unroll
    for (int j = 32; j >= 1; j >>= 1) {
      const unsigned long long o = __shfl_xor(m, j, 64);
      const unsigned long long lo = o < m ? o : m;
      const unsigned long long hi = o < m ? m : o;
      m = ((lane & j) == 0) ? lo : hi;
    }
    if (lane < 32) knn[gid * 32 + lane] = (int)(unsigned int)m;
  }
}

// ---------------- phase kernels: MFMA fused GEMMs ----------------------------
// Wave w owns cols 32w..32w+31. Per lane: m = lane&31 (A row / D col), q2 = lane>>5.
// A layout: A[m=lane&31][k=q2*8+j]; B layout: B^T[n=lane&31][k=q2*8+j];
// C/D layout: col=lane&31, row=(reg&3)+8*(reg>>2)+4*q2  [m74/m101-verified].
template <int PHASE>
__global__ __launch_bounds__(256, 4) void kphase(
    const float* __restrict__ x, const int* __restrict__ indx,
    const int* __restrict__ knn, const float* __restrict__ wt1lo,
    const float* __restrict__ b1, const unsigned short* __restrict__ w1bh,
    const unsigned short* __restrict__ w2b, const float* __restrict__ b2,
    const float* __restrict__ st1, float* __restrict__ part,
    float* __restrict__ mout) {
  __shared__ __align__(16) float sx[64];
  __shared__ int nbi[32];
  __shared__ float red[256];
  __shared__ __align__(16) unsigned short h1[PHASE == 2 ? 32 * 136 : 8];

  const int tid = threadIdx.x;
  const int w = tid >> 6;
  const int lane = tid & 63;
  const int m = lane & 31, q2 = lane >> 5;
  const int col = (w << 5) + m;              // output channel of this lane
  const int bo = tid & 127, bh = tid >> 7;   // base-dot mapping

  // group-invariant operands in registers
  bf8 bf1[4];
#pragma unroll
  for (int t = 0; t < 4; ++t)
    bf1[t] = *(const bf8*)&w1bh[col * 64 + t * 16 + q2 * 8];
  bf8 bf2[8];
  float s1 = 0.f, t1 = 0.f, b2v = 0.f;
  if constexpr (PHASE == 2) {
#pragma unroll
    for (int t = 0; t < 8; ++t)
      bf2[t] = *(const bf8*)&w2b[col * 128 + t * 16 + q2 * 8];
    s1 = st1[col];
    t1 = st1[128 + col];
    b2v = b2[col];
  }
  (void)w2b; (void)b2; (void)st1; (void)mout;
  const float b1v = (bh == 0) ? b1[bo] : 0.f;

  float sum = 0.f, ssq = 0.f;

#pragma unroll 1
  for (int g = 0; g < GPB_; ++g) {
    const int gid = blockIdx.x * GPB_ + g;
    const int b = gid >> 11, s = gid & 2047;
    const float* xb = x + (size_t)b * (N_ * 64);
    __syncthreads();                         // LDS reuse guard
    if (tid < 64) sx[tid] = xb[(size_t)indx[s] * 64 + tid];
    if (tid >= 64 && tid < 96) nbi[tid - 64] = knn[gid * 32 + (tid - 64)];
    __syncthreads();

    // exact fp32 base half-dots: base[o] = b1[o] + sx . w1[o][0:64]
    float a = b1v;
#pragma unroll 8
    for (int i = 0; i < 32; ++i) {
      const int ii = (bh << 5) + i;
      a = fmaf(sx[ii], wt1lo[ii * 128 + bo], a);
    }
    red[tid] = a;

    // A1 frags: d = x[nb[m]] - sx, bf16, in-register
    const float* xr = xb + (size_t)nbi[m] * 64;
    bf8 af[4];
#pragma unroll
    for (int t = 0; t < 4; ++t) {
      const int k0 = t * 16 + q2 * 8;
      const float4 xa = *(const float4*)(xr + k0);
      const float4 xc = *(const float4*)(xr + k0 + 4);
      const float4 sa = *(const float4*)(sx + k0);
      const float4 sc = *(const float4*)(sx + k0 + 4);
      union { bf8 v; unsigned int u[4]; } uu;
      uu.u[0] = bfpair(xa.x - sa.x, xa.y - sa.y);
      uu.u[1] = bfpair(xa.z - sa.z, xa.w - sa.w);
      uu.u[2] = bfpair(xc.x - sc.x, xc.y - sc.y);
      uu.u[3] = bfpair(xc.z - sc.z, xc.w - sc.w);
      af[t] = uu.v;
    }
    __syncthreads();                         // red ready

    const float bb = red[col] + red[128 + col];
    f32x16 acc;
#pragma unroll
    for (int r = 0; r < 16; ++r) acc[r] = bb;
#pragma unroll
    for (int t = 0; t < 4; ++t)
      acc = __builtin_amdgcn_mfma_f32_32x32x16_bf16(af[t], bf1[t], acc, 0, 0, 0);

    if constexpr (PHASE == 1) {
#pragma unroll
      for (int r = 0; r < 16; ++r) {
        const float v = acc[r];
        sum += v;
        ssq = fmaf(v, v, ssq);
      }
    } else {
      // bn1 + relu -> h1 bf16 in LDS (C-layout scatter, row stride 136)
#pragma unroll
      for (int r = 0; r < 16; ++r) {
        const float hv = fmaxf(0.f, fmaf(acc[r], s1, t1));
        const int row = (r & 3) + ((r >> 2) << 3) + (q2 << 2);
        h1[row * 136 + col] = (unsigned short)bf1u(hv);
      }
      __syncthreads();                       // h1 ready

      f32x16 acc2;
#pragma unroll
      for (int r = 0; r < 16; ++r) acc2[r] = b2v;
#pragma unroll
      for (int t = 0; t < 8; ++t) {
        const bf8 a2 = *(const bf8*)&h1[m * 136 + t * 16 + q2 * 8];
        acc2 = __builtin_amdgcn_mfma_f32_32x32x16_bf16(a2, bf2[t], acc2, 0, 0, 0);
      }

      float mx = -1e30f;
#pragma unroll
      for (int r = 0; r < 16; ++r) {
        const float v = acc2[r];
        sum += v;
        ssq = fmaf(v, v, ssq);
        mx = fmaxf(mx, v);
      }
      mx = fmaxf(mx, __shfl_xor(mx, 32, 64));
      if (lane < 32) mout[(size_t)gid * 128 + col] = mx;
    }
  }

  // channel partials: each channel owned by exactly one wave
  sum += __shfl_xor(sum, 32, 64);
  ssq += __shfl_xor(ssq, 32, 64);
  if (lane < 32) {
    part[blockIdx.x * 256 + col] = sum;
    part[blockIdx.x * 256 + 128 + col] = ssq;
  }
}

// ---------------- stats finalize (double precision) --------------------------
__global__ __launch_bounds__(1024) void kreduce(const float* __restrict__ part,
                                                const float* __restrict__ gam,
                                                const float* __restrict__ bet,
                                                float* __restrict__ st) {
  __shared__ double redd[4][256];
  const int tid = threadIdx.x;
  const int c = tid & 255, pq = tid >> 8;
  double acc = 0.0;
  for (int row = pq; row < 2048; row += 4) acc += (double)part[row * 256 + c];
  redd[pq][c] = acc;
  __syncthreads();
  if (tid < 256) redd[0][tid] = redd[0][tid] + redd[1][tid] + redd[2][tid] + redd[3][tid];
  __syncthreads();
  if (tid < 128) {
    const double Sv = redd[0][tid], SSv = redd[0][128 + tid];
    const double cnt = 524288.0;                 // B*S*K
    const double mean = Sv / cnt;
    const double var = SSv / cnt - mean * mean;
    const double scale = (double)gam[tid] / sqrt(var + 1e-5);
    st[tid] = (float)scale;
    st[128 + tid] = (float)((double)bet[tid] - mean * scale);
  }
}

// ---------------- final: out = relu(scale2 * max_k(y2) + shift2) -------------
__global__ __launch_bounds__(256) void kout(const float* __restrict__ m,
                                            const float* __restrict__ st2,
                                            float* __restrict__ out) {
  const int e4 = blockIdx.x * 256 + threadIdx.x;  // 524288 float4s
  const int o0 = (e4 & 31) * 4;
  const float4 v = ((const float4*)m)[e4];
  const float4 sc = *(const float4*)&st2[o0];
  const float4 sh = *(const float4*)&st2[128 + o0];
  float4 r;
  r.x = fmaxf(0.f, fmaf(v.x, sc.x, sh.x));
  r.y = fmaxf(0.f, fmaf(v.y, sc.y, sh.y));
  r.z = fmaxf(0.f, fmaf(v.z, sc.z, sh.z));
  r.w = fmaxf(0.f, fmaf(v.w, sc.w, sh.w));
  ((float4*)out)[e4] = r;
}

extern "C" void kernel_launch(void* const* d_in, const int* in_sizes, int n_in,
                              void* d_out, int out_size, void* d_ws, size_t ws_size,
                              hipStream_t stream) {
  (void)in_sizes; (void)n_in; (void)out_size; (void)ws_size;
  const float* x    = (const float*)d_in[0];
  const float* coor = (const float*)d_in[1];
  const int*   indx = (const int*)d_in[2];
  const float* w1   = (const float*)d_in[3];
  const float* b1   = (const float*)d_in[4];
  const float* g1   = (const float*)d_in[5];
  const float* be1  = (const float*)d_in[6];
  const float* w2   = (const float*)d_in[7];
  const float* b2   = (const float*)d_in[8];
  const float* g2   = (const float*)d_in[9];
  const float* be2  = (const float*)d_in[10];
  float* out = (float*)d_out;

  char* ws = (char*)d_ws;
  int*            knn   = (int*)(ws + 0);
  float*          mbuf  = (float*)(ws + 2097152);
  float*          part1 = (float*)(ws + 10485760);
  float4*         coor4 = (float4*)(ws + 10485760); // aliases part1 (disjoint lifetime)
  float*          part2 = (float*)(ws + 12582912);
  float*          wt1lo = (float*)(ws + 14680064);
  unsigned short* w1bh  = (unsigned short*)(ws + 14712832);
  unsigned short* w2b   = (unsigned short*)(ws + 14729216);
  float*          st1   = (float*)(ws + 14761984);
  float*          st2   = (float*)(ws + 14763008);

  float* outc = out + 2097152;   // sampled_coor region of d_out

  kprep<<<576, 256, 0, stream>>>(w1, w2, coor, indx, wt1lo, w1bh, w2b, outc, coor4);
  kknn<<<16384, 256, 0, stream>>>(coor4, indx, knn);
  kphase<1><<<2048, 256, 0, stream>>>(x, indx, knn, wt1lo, b1, w1bh, w2b, b2, nullptr,
                                      part1, nullptr);
  kreduce<<<1, 1024, 0, stream>>>(part1, g1, be1, st1);
  kphase<2><<<2048, 256, 0, stream>>>(x, indx, knn, wt1lo, b1, w1bh, w2b, b2, st1,
                                      part2, mbuf);
  kreduce<<<1, 1024, 0, stream>>>(part2, g2, be2, st2);
  kout<<<2048, 256, 0, stream>>>(mbuf, st2, out);
}

// Round 7
// 724.815 us; speedup vs baseline: 4.8468x; 1.0449x over previous
//
#include <hip/hip_runtime.h>
#include <stdint.h>

// sample_and_group: B=8 N=8192 C=64 S=2048 K=32 OUT=128
// out = (out[8,2048,128], sampled_coor[8,2048,3]) concatenated in d_out (float32).
//
// R6 fix: R5's dist[32]-in-registers spilled to scratch (239MB writes); R6's
// recompute variant crashed (multi-change, unattributable). This round: revert
// to the R5-passing structure exactly (same barriers, same launch bounds) with
// ONE change: dist[32] lives in LDS (sdist[it*256+tid], 32KB/block,
// conflict-free, 4 blocks/CU unchanged). Kills both the scratch traffic and
// pass-3's second coor4 read (pass 3 now reads LDS, halving L2 traffic).
//
// Workspace layout (bytes):
//   [0,2MB)        knn indices  int32[16384*32]
//   [2MB,10MB)     m = max_k y2 f32[16384*128]
//   [10MB,11MB)    coor4 float4[8*8192]   (ALIASES part1; kknn-only lifetime)
//   [10MB,12MB)    partials1    f32[2048*256]
//   [12MB,14MB)    partials2    f32[2048*256]
//   [14MB,+32KB)   wt1lo fp32 [i=0..63][o]   (base dot, transposed)
//   [..,+16KB)     w1bh  bf16 [o][i=0..63]   (hi half of w1)
//   [..,+32KB)     w2b   bf16 [o][k=0..127]
//   [..,+1KB)      stats1 (scale[128], shift[128])
//   [..,+1KB)      stats2

#define N_    8192
#define GPB_  8       // groups per block in phase kernels

typedef __attribute__((ext_vector_type(8))) short bf8;
typedef __attribute__((ext_vector_type(16))) float f32x16;

__device__ __forceinline__ unsigned int bf1u(float f) {   // RNE fp32->bf16 bits
  unsigned int u = __float_as_uint(f);
  return (u + 0x7fffu + ((u >> 16) & 1u)) >> 16;
}
__device__ __forceinline__ unsigned int bfpair(float lo, float hi) {
  return bf1u(lo) | (bf1u(hi) << 16);
}

// ---------------- prep: weight layouts + coor4 pack + sampled_coor ------------
__global__ __launch_bounds__(256) void kprep(const float* __restrict__ w1,
                                             const float* __restrict__ w2,
                                             const float* __restrict__ coor,
                                             const int* __restrict__ indx,
                                             float* __restrict__ wt1lo,
                                             unsigned short* __restrict__ w1bh,
                                             unsigned short* __restrict__ w2b,
                                             float* __restrict__ outc,
                                             float4* __restrict__ coor4) {
  int e = blockIdx.x * 256 + threadIdx.x;   // grid is exactly 576*256 = 147456
  if (e < 8192) {                            // wt1lo[i][o] = w1[o][i], i<64
    int i = e >> 7, o = e & 127;
    wt1lo[e] = w1[o * 128 + i];
  } else if (e < 16384) {                    // w1bh[o][i] = bf16(w1[o][64+i])
    int e2 = e - 8192;
    int o = e2 >> 6, i = e2 & 63;
    w1bh[e2] = (unsigned short)bf1u(w1[o * 128 + 64 + i]);
  } else if (e < 32768) {                    // w2b[o][k] = bf16(w2[o][k])
    int e2 = e - 16384;
    w2b[e2] = (unsigned short)bf1u(w2[e2]);
  } else if (e < 81920) {
    int e2 = e - 32768;                      // 0..49151 sampled_coor
    int bs = e2 / 3, c = e2 - bs * 3;
    int b = bs >> 11, s = bs & 2047;
    outc[e2] = coor[(b * N_ + indx[s]) * 3 + c];
  } else {
    int p = e - 81920;                       // 0..65535 coor4 pack
    const float* src = coor + (size_t)p * 3;
    coor4[p] = make_float4(src[0], src[1], src[2], 0.f);
  }
}

// ---------------- KNN: threshold-select, one query per 256-thread block -------
// Output = SET of 32 smallest keys (dist_bits<<32 | idx); order arbitrary
// (downstream max/mean/var are permutation-invariant over K).
__global__ __launch_bounds__(256, 4) void kknn(const float4* __restrict__ coor4,
                                               const int* __restrict__ indx,
                                               int* __restrict__ knn) {
  __shared__ float sdist[32 * 256];           // 32KB: dist[it][tid], conflict-free
  __shared__ float smin[128];                 // 4 waves x 32 smallest thread-mins
  __shared__ float smrg[64];                  // 2 pairwise-merged 32-lists
  __shared__ float sT;
  __shared__ unsigned long long cands[128];
  __shared__ unsigned long long ssort[128];
  __shared__ int ccnt;

  const int gid = blockIdx.x;
  const int b = gid >> 11, s = gid & 2047;
  const int tid = threadIdx.x;
  const int w = tid >> 6, lane = tid & 63;
  const float4* cb = coor4 + ((size_t)b << 13);
  const float4 q = cb[indx[s]];

  // pass 1: 32 exact distances -> LDS; track thread-min
  float dmin = 3.4e38f;
#pragma unroll 8
  for (int it = 0; it < 32; ++it) {
    const float4 c = cb[tid + (it << 8)];
    const float dx = __fsub_rn(c.x, q.x);
    const float dy = __fsub_rn(c.y, q.y);
    const float dz = __fsub_rn(c.z, q.z);
    const float d =
        __fadd_rn(__fadd_rn(__fmul_rn(dx, dx), __fmul_rn(dy, dy)), __fmul_rn(dz, dz));
    sdist[it * 256 + tid] = d;
    dmin = fminf(dmin, d);
  }
  if (tid == 0) ccnt = 0;
  if (tid < 128) cands[tid] = ~0ULL;

  // pass 2: T = exact 32nd smallest of the 256 thread-mins
  // (T >= d32: at most 31 elements lie strictly below d32, so at most 31
  //  thread-mins do; the 32nd-smallest min is >= d32.)
  float v = dmin;                             // per-wave bitonic sort (ascending)
#pragma unroll
  for (int k = 2; k <= 64; k <<= 1) {
#pragma unroll
    for (int j = k >> 1; j >= 1; j >>= 1) {
      const float o = __shfl_xor(v, j, 64);
      const bool dirAsc = ((lane & k) == 0);
      const bool lower = ((lane & j) == 0);
      const float lo = fminf(v, o), hi = fmaxf(v, o);
      v = (dirAsc == lower) ? lo : hi;
    }
  }
  if (lane < 32) smin[w * 32 + lane] = v;
  __syncthreads();
  if (w < 2) {                                // merge lists (2w, 2w+1) -> 32 smallest
    float a = (lane < 32) ? smin[w * 64 + lane] : smin[w * 64 + 32 + (63 - lane)];
#pragma unroll
    for (int j = 32; j >= 1; j >>= 1) {
      const float o = __shfl_xor(a, j, 64);
      const float lo = fminf(a, o), hi = fmaxf(a, o);
      a = ((lane & j) == 0) ? lo : hi;
    }
    if (lane < 32) smrg[w * 32 + lane] = a;
  }
  __syncthreads();
  if (w == 0) {                               // final merge -> 32nd smallest value
    float a = (lane < 32) ? smrg[lane] : smrg[32 + (63 - lane)];
#pragma unroll
    for (int j = 32; j >= 1; j >>= 1) {
      const float o = __shfl_xor(a, j, 64);
      const float lo = fminf(a, o), hi = fmaxf(a, o);
      a = ((lane & j) == 0) ? lo : hi;
    }
    if (lane == 31) sT = a;
  }
  __syncthreads();
  const float T = sT;

  // pass 3: compact candidates (dist <= T) from LDS; expected ~34-40, cap 128
#pragma unroll 8
  for (int it = 0; it < 32; ++it) {
    const float d = sdist[it * 256 + tid];
    if (d <= T) {
      const int pos = atomicAdd(&ccnt, 1);
      if (pos < 128)
        cands[pos] = ((unsigned long long)__float_as_uint(d) << 32) |
                     (unsigned int)(tid + (it << 8));
    }
  }
  __syncthreads();

  // pass 4: exact top-32 of <=128 candidates by u64 key
  if (w < 2) {                                // two parallel bitonic sort-64s
    unsigned long long kv = cands[w * 64 + lane];
#pragma unroll
    for (int k = 2; k <= 64; k <<= 1) {
#pragma unroll
      for (int j = k >> 1; j >= 1; j >>= 1) {
        const unsigned long long o = __shfl_xor(kv, j, 64);
        const bool dirAsc = ((lane & k) == 0);
        const bool lower = ((lane & j) == 0);
        const unsigned long long lo = o < kv ? o : kv;
        const unsigned long long hi = o < kv ? kv : o;
        kv = (dirAsc == lower) ? lo : hi;
      }
    }
    ssort[w * 64 + lane] = kv;
  }
  __syncthreads();
  if (w == 0) {                               // reverse-merge; lo-half holds 64 smallest
    const unsigned long long a = ssort[lane];
    const unsigned long long b2 = ssort[64 + 63 - lane];
    unsigned long long m = a < b2 ? a : b2;   // bitonic 64-seq
#pragma unroll
    for (int j = 32; j >= 1; j >>= 1) {
      const unsigned long long o = __shfl_xor(m, j, 64);
      const unsigned long long lo = o < m ? o : m;
      const unsigned long long hi = o < m ? m : o;
      m = ((lane & j) == 0) ? lo : hi;
    }
    if (lane < 32) knn[gid * 32 + lane] = (int)(unsigned int)m;
  }
}

// ---------------- phase kernels: MFMA fused GEMMs ----------------------------
// Wave w owns cols 32w..32w+31. Per lane: m = lane&31 (A row / D col), q2 = lane>>5.
// A layout: A[m=lane&31][k=q2*8+j]; B layout: B^T[n=lane&31][k=q2*8+j];
// C/D layout: col=lane&31, row=(reg&3)+8*(reg>>2)+4*q2  [m74/m101-verified].
template <int PHASE>
__global__ __launch_bounds__(256, 4) void kphase(
    const float* __restrict__ x, const int* __restrict__ indx,
    const int* __restrict__ knn, const float* __restrict__ wt1lo,
    const float* __restrict__ b1, const unsigned short* __restrict__ w1bh,
    const unsigned short* __restrict__ w2b, const float* __restrict__ b2,
    const float* __restrict__ st1, float* __restrict__ part,
    float* __restrict__ mout) {
  __shared__ __align__(16) float sx[64];
  __shared__ int nbi[32];
  __shared__ float red[256];
  __shared__ __align__(16) unsigned short h1[PHASE == 2 ? 32 * 136 : 8];

  const int tid = threadIdx.x;
  const int w = tid >> 6;
  const int lane = tid & 63;
  const int m = lane & 31, q2 = lane >> 5;
  const int col = (w << 5) + m;              // output channel of this lane
  const int bo = tid & 127, bh = tid >> 7;   // base-dot mapping

  // group-invariant operands in registers
  bf8 bf1[4];
#pragma unroll
  for (int t = 0; t < 4; ++t)
    bf1[t] = *(const bf8*)&w1bh[col * 64 + t * 16 + q2 * 8];
  bf8 bf2[8];
  float s1 = 0.f, t1 = 0.f, b2v = 0.f;
  if constexpr (PHASE == 2) {
#pragma unroll
    for (int t = 0; t < 8; ++t)
      bf2[t] = *(const bf8*)&w2b[col * 128 + t * 16 + q2 * 8];
    s1 = st1[col];
    t1 = st1[128 + col];
    b2v = b2[col];
  }
  (void)w2b; (void)b2; (void)st1; (void)mout;
  const float b1v = (bh == 0) ? b1[bo] : 0.f;

  float sum = 0.f, ssq = 0.f;

#pragma unroll 1
  for (int g = 0; g < GPB_; ++g) {
    const int gid = blockIdx.x * GPB_ + g;
    const int b = gid >> 11, s = gid & 2047;
    const float* xb = x + (size_t)b * (N_ * 64);
    __syncthreads();                         // LDS reuse guard
    if (tid < 64) sx[tid] = xb[(size_t)indx[s] * 64 + tid];
    if (tid >= 64 && tid < 96) nbi[tid - 64] = knn[gid * 32 + (tid - 64)];
    __syncthreads();

    // exact fp32 base half-dots: base[o] = b1[o] + sx . w1[o][0:64]
    float a = b1v;
#pragma unroll 8
    for (int i = 0; i < 32; ++i) {
      const int ii = (bh << 5) + i;
      a = fmaf(sx[ii], wt1lo[ii * 128 + bo], a);
    }
    red[tid] = a;

    // A1 frags: d = x[nb[m]] - sx, bf16, in-register
    const float* xr = xb + (size_t)nbi[m] * 64;
    bf8 af[4];
#pragma unroll
    for (int t = 0; t < 4; ++t) {
      const int k0 = t * 16 + q2 * 8;
      const float4 xa = *(const float4*)(xr + k0);
      const float4 xc = *(const float4*)(xr + k0 + 4);
      const float4 sa = *(const float4*)(sx + k0);
      const float4 sc = *(const float4*)(sx + k0 + 4);
      union { bf8 v; unsigned int u[4]; } uu;
      uu.u[0] = bfpair(xa.x - sa.x, xa.y - sa.y);
      uu.u[1] = bfpair(xa.z - sa.z, xa.w - sa.w);
      uu.u[2] = bfpair(xc.x - sc.x, xc.y - sc.y);
      uu.u[3] = bfpair(xc.z - sc.z, xc.w - sc.w);
      af[t] = uu.v;
    }
    __syncthreads();                         // red ready

    const float bb = red[col] + red[128 + col];
    f32x16 acc;
#pragma unroll
    for (int r = 0; r < 16; ++r) acc[r] = bb;
#pragma unroll
    for (int t = 0; t < 4; ++t)
      acc = __builtin_amdgcn_mfma_f32_32x32x16_bf16(af[t], bf1[t], acc, 0, 0, 0);

    if constexpr (PHASE == 1) {
#pragma unroll
      for (int r = 0; r < 16; ++r) {
        const float v = acc[r];
        sum += v;
        ssq = fmaf(v, v, ssq);
      }
    } else {
      // bn1 + relu -> h1 bf16 in LDS (C-layout scatter, row stride 136)
#pragma unroll
      for (int r = 0; r < 16; ++r) {
        const float hv = fmaxf(0.f, fmaf(acc[r], s1, t1));
        const int row = (r & 3) + ((r >> 2) << 3) + (q2 << 2);
        h1[row * 136 + col] = (unsigned short)bf1u(hv);
      }
      __syncthreads();                       // h1 ready

      f32x16 acc2;
#pragma unroll
      for (int r = 0; r < 16; ++r) acc2[r] = b2v;
#pragma unroll
      for (int t = 0; t < 8; ++t) {
        const bf8 a2 = *(const bf8*)&h1[m * 136 + t * 16 + q2 * 8];
        acc2 = __builtin_amdgcn_mfma_f32_32x32x16_bf16(a2, bf2[t], acc2, 0, 0, 0);
      }

      float mx = -1e30f;
#pragma unroll
      for (int r = 0; r < 16; ++r) {
        const float v = acc2[r];
        sum += v;
        ssq = fmaf(v, v, ssq);
        mx = fmaxf(mx, v);
      }
      mx = fmaxf(mx, __shfl_xor(mx, 32, 64));
      if (lane < 32) mout[(size_t)gid * 128 + col] = mx;
    }
  }

  // channel partials: each channel owned by exactly one wave
  sum += __shfl_xor(sum, 32, 64);
  ssq += __shfl_xor(ssq, 32, 64);
  if (lane < 32) {
    part[blockIdx.x * 256 + col] = sum;
    part[blockIdx.x * 256 + 128 + col] = ssq;
  }
}

// ---------------- stats finalize (double precision) --------------------------
__global__ __launch_bounds__(1024) void kreduce(const float* __restrict__ part,
                                                const float* __restrict__ gam,
                                                const float* __restrict__ bet,
                                                float* __restrict__ st) {
  __shared__ double redd[4][256];
  const int tid = threadIdx.x;
  const int c = tid & 255, pq = tid >> 8;
  double acc = 0.0;
  for (int row = pq; row < 2048; row += 4) acc += (double)part[row * 256 + c];
  redd[pq][c] = acc;
  __syncthreads();
  if (tid < 256) redd[0][tid] = redd[0][tid] + redd[1][tid] + redd[2][tid] + redd[3][tid];
  __syncthreads();
  if (tid < 128) {
    const double Sv = redd[0][tid], SSv = redd[0][128 + tid];
    const double cnt = 524288.0;                 // B*S*K
    const double mean = Sv / cnt;
    const double var = SSv / cnt - mean * mean;
    const double scale = (double)gam[tid] / sqrt(var + 1e-5);
    st[tid] = (float)scale;
    st[128 + tid] = (float)((double)bet[tid] - mean * scale);
  }
}

// ---------------- final: out = relu(scale2 * max_k(y2) + shift2) -------------
__global__ __launch_bounds__(256) void kout(const float* __restrict__ m,
                                            const float* __restrict__ st2,
                                            float* __restrict__ out) {
  const int e4 = blockIdx.x * 256 + threadIdx.x;  // 524288 float4s
  const int o0 = (e4 & 31) * 4;
  const float4 v = ((const float4*)m)[e4];
  const float4 sc = *(const float4*)&st2[o0];
  const float4 sh = *(const float4*)&st2[128 + o0];
  float4 r;
  r.x = fmaxf(0.f, fmaf(v.x, sc.x, sh.x));
  r.y = fmaxf(0.f, fmaf(v.y, sc.y, sh.y));
  r.z = fmaxf(0.f, fmaf(v.z, sc.z, sh.z));
  r.w = fmaxf(0.f, fmaf(v.w, sc.w, sh.w));
  ((float4*)out)[e4] = r;
}

extern "C" void kernel_launch(void* const* d_in, const int* in_sizes, int n_in,
                              void* d_out, int out_size, void* d_ws, size_t ws_size,
                              hipStream_t stream) {
  (void)in_sizes; (void)n_in; (void)out_size; (void)ws_size;
  const float* x    = (const float*)d_in[0];
  const float* coor = (const float*)d_in[1];
  const int*   indx = (const int*)d_in[2];
  const float* w1   = (const float*)d_in[3];
  const float* b1   = (const float*)d_in[4];
  const float* g1   = (const float*)d_in[5];
  const float* be1  = (const float*)d_in[6];
  const float* w2   = (const float*)d_in[7];
  const float* b2   = (const float*)d_in[8];
  const float* g2   = (const float*)d_in[9];
  const float* be2  = (const float*)d_in[10];
  float* out = (float*)d_out;

  char* ws = (char*)d_ws;
  int*            knn   = (int*)(ws + 0);
  float*          mbuf  = (float*)(ws + 2097152);
  float*          part1 = (float*)(ws + 10485760);
  float4*         coor4 = (float4*)(ws + 10485760); // aliases part1 (disjoint lifetime)
  float*          part2 = (float*)(ws + 12582912);
  float*          wt1lo = (float*)(ws + 14680064);
  unsigned short* w1bh  = (unsigned short*)(ws + 14712832);
  unsigned short* w2b   = (unsigned short*)(ws + 14729216);
  float*          st1   = (float*)(ws + 14761984);
  float*          st2   = (float*)(ws + 14763008);

  float* outc = out + 2097152;   // sampled_coor region of d_out

  kprep<<<576, 256, 0, stream>>>(w1, w2, coor, indx, wt1lo, w1bh, w2b, outc, coor4);
  kknn<<<16384, 256, 0, stream>>>(coor4, indx, knn);
  kphase<1><<<2048, 256, 0, stream>>>(x, indx, knn, wt1lo, b1, w1bh, w2b, b2, nullptr,
                                      part1, nullptr);
  kreduce<<<1, 1024, 0, stream>>>(part1, g1, be1, st1);
  kphase<2><<<2048, 256, 0, stream>>>(x, indx, knn, wt1lo, b1, w1bh, w2b, b2, st1,
                                      part2, mbuf);
  kreduce<<<1, 1024, 0, stream>>>(part2, g2, be2, st2);
  kout<<<2048, 256, 0, stream>>>(mbuf, st2, out);
}

// Round 8
// 616.755 us; speedup vs baseline: 5.6959x; 1.1752x over previous
//
#include <hip/hip_runtime.h>
#include <stdint.h>

// sample_and_group: B=8 N=8192 C=64 S=2048 K=32 OUT=128
// out = (out[8,2048,128], sampled_coor[8,2048,3]) concatenated in d_out (float32).
//
// R7 fix: phase kernels' A-frag build used 8 scattered global dwordx4/thread
// (each wave-inst touching ~32 cache lines -> TA/L1 serialization). Now the
// d-tile is staged through LDS with a coalesced map (thread = 8 floats of row
// tid>>3), packed to bf16 at stage time, stored at stride 68 bf16 and accessed
// as uint2 pairs (2-way bank aliasing = free). Values bit-identical to R7.
//
// Workspace layout (bytes):
//   [0,2MB)        knn indices  int32[16384*32]
//   [2MB,10MB)     m = max_k y2 f32[16384*128]
//   [10MB,11MB)    coor4 float4[8*8192]   (ALIASES part1; kknn-only lifetime)
//   [10MB,12MB)    partials1    f32[2048*256]
//   [12MB,14MB)    partials2    f32[2048*256]
//   [14MB,+32KB)   wt1lo fp32 [i=0..63][o]   (base dot, transposed)
//   [..,+16KB)     w1bh  bf16 [o][i=0..63]   (hi half of w1)
//   [..,+32KB)     w2b   bf16 [o][k=0..127]
//   [..,+1KB)      stats1 (scale[128], shift[128])
//   [..,+1KB)      stats2

#define N_    8192
#define GPB_  8       // groups per block in phase kernels

typedef __attribute__((ext_vector_type(8))) short bf8;
typedef __attribute__((ext_vector_type(16))) float f32x16;

__device__ __forceinline__ unsigned int bf1u(float f) {   // RNE fp32->bf16 bits
  unsigned int u = __float_as_uint(f);
  return (u + 0x7fffu + ((u >> 16) & 1u)) >> 16;
}
__device__ __forceinline__ unsigned int bfpair(float lo, float hi) {
  return bf1u(lo) | (bf1u(hi) << 16);
}

// ---------------- prep: weight layouts + coor4 pack + sampled_coor ------------
__global__ __launch_bounds__(256) void kprep(const float* __restrict__ w1,
                                             const float* __restrict__ w2,
                                             const float* __restrict__ coor,
                                             const int* __restrict__ indx,
                                             float* __restrict__ wt1lo,
                                             unsigned short* __restrict__ w1bh,
                                             unsigned short* __restrict__ w2b,
                                             float* __restrict__ outc,
                                             float4* __restrict__ coor4) {
  int e = blockIdx.x * 256 + threadIdx.x;   // grid is exactly 576*256 = 147456
  if (e < 8192) {                            // wt1lo[i][o] = w1[o][i], i<64
    int i = e >> 7, o = e & 127;
    wt1lo[e] = w1[o * 128 + i];
  } else if (e < 16384) {                    // w1bh[o][i] = bf16(w1[o][64+i])
    int e2 = e - 8192;
    int o = e2 >> 6, i = e2 & 63;
    w1bh[e2] = (unsigned short)bf1u(w1[o * 128 + 64 + i]);
  } else if (e < 32768) {                    // w2b[o][k] = bf16(w2[o][k])
    int e2 = e - 16384;
    w2b[e2] = (unsigned short)bf1u(w2[e2]);
  } else if (e < 81920) {
    int e2 = e - 32768;                      // 0..49151 sampled_coor
    int bs = e2 / 3, c = e2 - bs * 3;
    int b = bs >> 11, s = bs & 2047;
    outc[e2] = coor[(b * N_ + indx[s]) * 3 + c];
  } else {
    int p = e - 81920;                       // 0..65535 coor4 pack
    const float* src = coor + (size_t)p * 3;
    coor4[p] = make_float4(src[0], src[1], src[2], 0.f);
  }
}

// ---------------- KNN: threshold-select, one query per 256-thread block -------
// Output = SET of 32 smallest keys (dist_bits<<32 | idx); order arbitrary
// (downstream max/mean/var are permutation-invariant over K).
__global__ __launch_bounds__(256, 4) void kknn(const float4* __restrict__ coor4,
                                               const int* __restrict__ indx,
                                               int* __restrict__ knn) {
  __shared__ float sdist[32 * 256];           // 32KB: dist[it][tid], conflict-free
  __shared__ float smin[128];                 // 4 waves x 32 smallest thread-mins
  __shared__ float smrg[64];                  // 2 pairwise-merged 32-lists
  __shared__ float sT;
  __shared__ unsigned long long cands[128];
  __shared__ unsigned long long ssort[128];
  __shared__ int ccnt;

  const int gid = blockIdx.x;
  const int b = gid >> 11, s = gid & 2047;
  const int tid = threadIdx.x;
  const int w = tid >> 6, lane = tid & 63;
  const float4* cb = coor4 + ((size_t)b << 13);
  const float4 q = cb[indx[s]];

  // pass 1: 32 exact distances -> LDS; track thread-min
  float dmin = 3.4e38f;
#pragma unroll 8
  for (int it = 0; it < 32; ++it) {
    const float4 c = cb[tid + (it << 8)];
    const float dx = __fsub_rn(c.x, q.x);
    const float dy = __fsub_rn(c.y, q.y);
    const float dz = __fsub_rn(c.z, q.z);
    const float d =
        __fadd_rn(__fadd_rn(__fmul_rn(dx, dx), __fmul_rn(dy, dy)), __fmul_rn(dz, dz));
    sdist[it * 256 + tid] = d;
    dmin = fminf(dmin, d);
  }
  if (tid == 0) ccnt = 0;
  if (tid < 128) cands[tid] = ~0ULL;

  // pass 2: T = exact 32nd smallest of the 256 thread-mins
  // (T >= d32: at most 31 elements lie strictly below d32, so at most 31
  //  thread-mins do; the 32nd-smallest min is >= d32.)
  float v = dmin;                             // per-wave bitonic sort (ascending)
#pragma unroll
  for (int k = 2; k <= 64; k <<= 1) {
#pragma unroll
    for (int j = k >> 1; j >= 1; j >>= 1) {
      const float o = __shfl_xor(v, j, 64);
      const bool dirAsc = ((lane & k) == 0);
      const bool lower = ((lane & j) == 0);
      const float lo = fminf(v, o), hi = fmaxf(v, o);
      v = (dirAsc == lower) ? lo : hi;
    }
  }
  if (lane < 32) smin[w * 32 + lane] = v;
  __syncthreads();
  if (w < 2) {                                // merge lists (2w, 2w+1) -> 32 smallest
    float a = (lane < 32) ? smin[w * 64 + lane] : smin[w * 64 + 32 + (63 - lane)];
#pragma unroll
    for (int j = 32; j >= 1; j >>= 1) {
      const float o = __shfl_xor(a, j, 64);
      const float lo = fminf(a, o), hi = fmaxf(a, o);
      a = ((lane & j) == 0) ? lo : hi;
    }
    if (lane < 32) smrg[w * 32 + lane] = a;
  }
  __syncthreads();
  if (w == 0) {                               // final merge -> 32nd smallest value
    float a = (lane < 32) ? smrg[lane] : smrg[32 + (63 - lane)];
#pragma unroll
    for (int j = 32; j >= 1; j >>= 1) {
      const float o = __shfl_xor(a, j, 64);
      const float lo = fminf(a, o), hi = fmaxf(a, o);
      a = ((lane & j) == 0) ? lo : hi;
    }
    if (lane == 31) sT = a;
  }
  __syncthreads();
  const float T = sT;

  // pass 3: compact candidates (dist <= T) from LDS; expected ~34-40, cap 128
#pragma unroll 8
  for (int it = 0; it < 32; ++it) {
    const float d = sdist[it * 256 + tid];
    if (d <= T) {
      const int pos = atomicAdd(&ccnt, 1);
      if (pos < 128)
        cands[pos] = ((unsigned long long)__float_as_uint(d) << 32) |
                     (unsigned int)(tid + (it << 8));
    }
  }
  __syncthreads();

  // pass 4: exact top-32 of <=128 candidates by u64 key
  if (w < 2) {                                // two parallel bitonic sort-64s
    unsigned long long kv = cands[w * 64 + lane];
#pragma unroll
    for (int k = 2; k <= 64; k <<= 1) {
#pragma unroll
      for (int j = k >> 1; j >= 1; j >>= 1) {
        const unsigned long long o = __shfl_xor(kv, j, 64);
        const bool dirAsc = ((lane & k) == 0);
        const bool lower = ((lane & j) == 0);
        const unsigned long long lo = o < kv ? o : kv;
        const unsigned long long hi = o < kv ? kv : o;
        kv = (dirAsc == lower) ? lo : hi;
      }
    }
    ssort[w * 64 + lane] = kv;
  }
  __syncthreads();
  if (w == 0) {                               // reverse-merge; lo-half holds 64 smallest
    const unsigned long long a = ssort[lane];
    const unsigned long long b2 = ssort[64 + 63 - lane];
    unsigned long long m = a < b2 ? a : b2;   // bitonic 64-seq
#pragma unroll
    for (int j = 32; j >= 1; j >>= 1) {
      const unsigned long long o = __shfl_xor(m, j, 64);
      const unsigned long long lo = o < m ? o : m;
      const unsigned long long hi = o < m ? m : o;
      m = ((lane & j) == 0) ? lo : hi;
    }
    if (lane < 32) knn[gid * 32 + lane] = (int)(unsigned int)m;
  }
}

// ---------------- phase kernels: MFMA fused GEMMs ----------------------------
// Wave w owns cols 32w..32w+31. Per lane: m = lane&31 (A row / D col), q2 = lane>>5.
// A layout: A[m=lane&31][k=q2*8+j]; B layout: B^T[n=lane&31][k=q2*8+j];
// C/D layout: col=lane&31, row=(reg&3)+8*(reg>>2)+4*q2  [m74/m101-verified].
// d-tile: LDS bf16, stride 68 (136B rows, uint2 ops -> 2-way aliasing = free).
template <int PHASE>
__global__ __launch_bounds__(256, 4) void kphase(
    const float* __restrict__ x, const int* __restrict__ indx,
    const int* __restrict__ knn, const float* __restrict__ wt1lo,
    const float* __restrict__ b1, const unsigned short* __restrict__ w1bh,
    const unsigned short* __restrict__ w2b, const float* __restrict__ b2,
    const float* __restrict__ st1, float* __restrict__ part,
    float* __restrict__ mout) {
  __shared__ __align__(16) float sx[64];
  __shared__ int nbi[32];
  __shared__ float red[256];
  __shared__ __align__(16) unsigned short dls[32 * 68 + 8];
  __shared__ __align__(16) unsigned short h1[PHASE == 2 ? 32 * 136 : 8];

  const int tid = threadIdx.x;
  const int w = tid >> 6;
  const int lane = tid & 63;
  const int m = lane & 31, q2 = lane >> 5;
  const int col = (w << 5) + m;              // output channel of this lane
  const int bo = tid & 127, bh = tid >> 7;   // base-dot mapping
  const int r8 = tid >> 3, c8 = (tid & 7) * 8;  // staging map: row, col-base

  // group-invariant operands in registers
  bf8 bf1[4];
#pragma unroll
  for (int t = 0; t < 4; ++t)
    bf1[t] = *(const bf8*)&w1bh[col * 64 + t * 16 + q2 * 8];
  bf8 bf2[8];
  float s1 = 0.f, t1 = 0.f, b2v = 0.f;
  if constexpr (PHASE == 2) {
#pragma unroll
    for (int t = 0; t < 8; ++t)
      bf2[t] = *(const bf8*)&w2b[col * 128 + t * 16 + q2 * 8];
    s1 = st1[col];
    t1 = st1[128 + col];
    b2v = b2[col];
  }
  (void)w2b; (void)b2; (void)st1; (void)mout;
  const float b1v = (bh == 0) ? b1[bo] : 0.f;

  float sum = 0.f, ssq = 0.f;

#pragma unroll 1
  for (int g = 0; g < GPB_; ++g) {
    const int gid = blockIdx.x * GPB_ + g;
    const int b = gid >> 11, s = gid & 2047;
    const float* xb = x + (size_t)b * (N_ * 64);
    __syncthreads();                         // LDS reuse guard
    if (tid < 64) sx[tid] = xb[(size_t)indx[s] * 64 + tid];
    if (tid >= 64 && tid < 96) nbi[tid - 64] = knn[gid * 32 + (tid - 64)];
    __syncthreads();

    // stage d = x[nb[r8]] - sx as bf16 into dls (coalesced: 8 lanes per row)
    {
      const float* xrow = xb + (size_t)nbi[r8] * 64 + c8;
      const float4 xa = *(const float4*)(xrow);
      const float4 xc = *(const float4*)(xrow + 4);
      const float4 sa = *(const float4*)(sx + c8);
      const float4 sc = *(const float4*)(sx + c8 + 4);
      uint2 lo, hi;
      lo.x = bfpair(xa.x - sa.x, xa.y - sa.y);
      lo.y = bfpair(xa.z - sa.z, xa.w - sa.w);
      hi.x = bfpair(xc.x - sc.x, xc.y - sc.y);
      hi.y = bfpair(xc.z - sc.z, xc.w - sc.w);
      *(uint2*)&dls[r8 * 68 + c8] = lo;      // byte addr 136*r8+16k: 8B-aligned
      *(uint2*)&dls[r8 * 68 + c8 + 4] = hi;
    }

    // exact fp32 base half-dots: base[o] = b1[o] + sx . w1[o][0:64]
    float a = b1v;
#pragma unroll 8
    for (int i = 0; i < 32; ++i) {
      const int ii = (bh << 5) + i;
      a = fmaf(sx[ii], wt1lo[ii * 128 + bo], a);
    }
    red[tid] = a;
    __syncthreads();                         // dls + red ready

    // A1 frags from LDS (uint2 pairs; values bit-identical to R7's build)
    bf8 af[4];
#pragma unroll
    for (int t = 0; t < 4; ++t) {
      union { bf8 v; uint2 u[2]; } fa;
      fa.u[0] = *(const uint2*)&dls[m * 68 + t * 16 + q2 * 8];
      fa.u[1] = *(const uint2*)&dls[m * 68 + t * 16 + q2 * 8 + 4];
      af[t] = fa.v;
    }

    const float bb = red[col] + red[128 + col];
    f32x16 acc;
#pragma unroll
    for (int r = 0; r < 16; ++r) acc[r] = bb;
#pragma unroll
    for (int t = 0; t < 4; ++t)
      acc = __builtin_amdgcn_mfma_f32_32x32x16_bf16(af[t], bf1[t], acc, 0, 0, 0);

    if constexpr (PHASE == 1) {
#pragma unroll
      for (int r = 0; r < 16; ++r) {
        const float v = acc[r];
        sum += v;
        ssq = fmaf(v, v, ssq);
      }
    } else {
      // bn1 + relu -> h1 bf16 in LDS (C-layout scatter, row stride 136)
#pragma unroll
      for (int r = 0; r < 16; ++r) {
        const float hv = fmaxf(0.f, fmaf(acc[r], s1, t1));
        const int row = (r & 3) + ((r >> 2) << 3) + (q2 << 2);
        h1[row * 136 + col] = (unsigned short)bf1u(hv);
      }
      __syncthreads();                       // h1 ready

      f32x16 acc2;
#pragma unroll
      for (int r = 0; r < 16; ++r) acc2[r] = b2v;
#pragma unroll
      for (int t = 0; t < 8; ++t) {
        const bf8 a2 = *(const bf8*)&h1[m * 136 + t * 16 + q2 * 8];
        acc2 = __builtin_amdgcn_mfma_f32_32x32x16_bf16(a2, bf2[t], acc2, 0, 0, 0);
      }

      float mx = -1e30f;
#pragma unroll
      for (int r = 0; r < 16; ++r) {
        const float v = acc2[r];
        sum += v;
        ssq = fmaf(v, v, ssq);
        mx = fmaxf(mx, v);
      }
      mx = fmaxf(mx, __shfl_xor(mx, 32, 64));
      if (lane < 32) mout[(size_t)gid * 128 + col] = mx;
    }
  }

  // channel partials: each channel owned by exactly one wave
  sum += __shfl_xor(sum, 32, 64);
  ssq += __shfl_xor(ssq, 32, 64);
  if (lane < 32) {
    part[blockIdx.x * 256 + col] = sum;
    part[blockIdx.x * 256 + 128 + col] = ssq;
  }
}

// ---------------- stats finalize (double precision) --------------------------
__global__ __launch_bounds__(1024) void kreduce(const float* __restrict__ part,
                                                const float* __restrict__ gam,
                                                const float* __restrict__ bet,
                                                float* __restrict__ st) {
  __shared__ double redd[4][256];
  const int tid = threadIdx.x;
  const int c = tid & 255, pq = tid >> 8;
  double acc = 0.0;
  for (int row = pq; row < 2048; row += 4) acc += (double)part[row * 256 + c];
  redd[pq][c] = acc;
  __syncthreads();
  if (tid < 256) redd[0][tid] = redd[0][tid] + redd[1][tid] + redd[2][tid] + redd[3][tid];
  __syncthreads();
  if (tid < 128) {
    const double Sv = redd[0][tid], SSv = redd[0][128 + tid];
    const double cnt = 524288.0;                 // B*S*K
    const double mean = Sv / cnt;
    const double var = SSv / cnt - mean * mean;
    const double scale = (double)gam[tid] / sqrt(var + 1e-5);
    st[tid] = (float)scale;
    st[128 + tid] = (float)((double)bet[tid] - mean * scale);
  }
}

// ---------------- final: out = relu(scale2 * max_k(y2) + shift2) -------------
__global__ __launch_bounds__(256) void kout(const float* __restrict__ m,
                                            const float* __restrict__ st2,
                                            float* __restrict__ out) {
  const int e4 = blockIdx.x * 256 + threadIdx.x;  // 524288 float4s
  const int o0 = (e4 & 31) * 4;
  const float4 v = ((const float4*)m)[e4];
  const float4 sc = *(const float4*)&st2[o0];
  const float4 sh = *(const float4*)&st2[128 + o0];
  float4 r;
  r.x = fmaxf(0.f, fmaf(v.x, sc.x, sh.x));
  r.y = fmaxf(0.f, fmaf(v.y, sc.y, sh.y));
  r.z = fmaxf(0.f, fmaf(v.z, sc.z, sh.z));
  r.w = fmaxf(0.f, fmaf(v.w, sc.w, sh.w));
  ((float4*)out)[e4] = r;
}

extern "C" void kernel_launch(void* const* d_in, const int* in_sizes, int n_in,
                              void* d_out, int out_size, void* d_ws, size_t ws_size,
                              hipStream_t stream) {
  (void)in_sizes; (void)n_in; (void)out_size; (void)ws_size;
  const float* x    = (const float*)d_in[0];
  const float* coor = (const float*)d_in[1];
  const int*   indx = (const int*)d_in[2];
  const float* w1   = (const float*)d_in[3];
  const float* b1   = (const float*)d_in[4];
  const float* g1   = (const float*)d_in[5];
  const float* be1  = (const float*)d_in[6];
  const float* w2   = (const float*)d_in[7];
  const float* b2   = (const float*)d_in[8];
  const float* g2   = (const float*)d_in[9];
  const float* be2  = (const float*)d_in[10];
  float* out = (float*)d_out;

  char* ws = (char*)d_ws;
  int*            knn   = (int*)(ws + 0);
  float*          mbuf  = (float*)(ws + 2097152);
  float*          part1 = (float*)(ws + 10485760);
  float4*         coor4 = (float4*)(ws + 10485760); // aliases part1 (disjoint lifetime)
  float*          part2 = (float*)(ws + 12582912);
  float*          wt1lo = (float*)(ws + 14680064);
  unsigned short* w1bh  = (unsigned short*)(ws + 14712832);
  unsigned short* w2b   = (unsigned short*)(ws + 14729216);
  float*          st1   = (float*)(ws + 14761984);
  float*          st2   = (float*)(ws + 14763008);

  float* outc = out + 2097152;   // sampled_coor region of d_out

  kprep<<<576, 256, 0, stream>>>(w1, w2, coor, indx, wt1lo, w1bh, w2b, outc, coor4);
  kknn<<<16384, 256, 0, stream>>>(coor4, indx, knn);
  kphase<1><<<2048, 256, 0, stream>>>(x, indx, knn, wt1lo, b1, w1bh, w2b, b2, nullptr,
                                      part1, nullptr);
  kreduce<<<1, 1024, 0, stream>>>(part1, g1, be1, st1);
  kphase<2><<<2048, 256, 0, stream>>>(x, indx, knn, wt1lo, b1, w1bh, w2b, b2, st1,
                                      part2, mbuf);
  kreduce<<<1, 1024, 0, stream>>>(part2, g2, be2, st2);
  kout<<<2048, 256, 0, stream>>>(mbuf, st2, out);
}

// Round 9
// 610.728 us; speedup vs baseline: 5.7522x; 1.0099x over previous
//
#include <hip/hip_runtime.h>
#include <stdint.h>

// sample_and_group: B=8 N=8192 C=64 S=2048 K=32 OUT=128
// out = (out[8,2048,128], sampled_coor[8,2048,3]) concatenated in d_out (float32).
//
// R8 fix: phases (~140us each) ran ~8x above compute floor. Suspects: per-group
// 32-deep serial fp32 base-dot with 32 global loads/thread, red[] LDS round-trip,
// 3-4 barriers/group. This round folds the base dot into the MFMA: layer-1 is
// one K=128 GEMM with A = [sx (bf16, cols 0-63) | d (cols 64-127)], B = full w1
// bf16 [o][k] (native row layout). Deletes base-dot, red, wt1lo, one barrier
// per group (phase1: 2 barriers, phase2: 3). kknn untouched (attribution).
//
// Workspace layout (bytes):
//   [0,2MB)        knn indices  int32[16384*32]
//   [2MB,10MB)     m = max_k y2 f32[16384*128]
//   [10MB,11MB)    coor4 float4[8*8192]   (ALIASES part1; kknn-only lifetime)
//   [10MB,12MB)    partials1    f32[2048*256]
//   [12MB,14MB)    partials2    f32[2048*256]
//   [14MB,+32KB)   w1b  bf16 [o][k=0..127]
//   [..,+32KB)     w2b  bf16 [o][k=0..127]
//   [..,+1KB)      stats1 (scale[128], shift[128])
//   [..,+1KB)      stats2

#define N_    8192
#define GPB_  8       // groups per block in phase kernels

typedef __attribute__((ext_vector_type(8))) short bf8;
typedef __attribute__((ext_vector_type(16))) float f32x16;

__device__ __forceinline__ unsigned int bf1u(float f) {   // RNE fp32->bf16 bits
  unsigned int u = __float_as_uint(f);
  return (u + 0x7fffu + ((u >> 16) & 1u)) >> 16;
}
__device__ __forceinline__ unsigned int bfpair(float lo, float hi) {
  return bf1u(lo) | (bf1u(hi) << 16);
}

// ---------------- prep: weight layouts + coor4 pack + sampled_coor ------------
__global__ __launch_bounds__(256) void kprep(const float* __restrict__ w1,
                                             const float* __restrict__ w2,
                                             const float* __restrict__ coor,
                                             const int* __restrict__ indx,
                                             unsigned short* __restrict__ w1b,
                                             unsigned short* __restrict__ w2b,
                                             float* __restrict__ outc,
                                             float4* __restrict__ coor4) {
  int e = blockIdx.x * 256 + threadIdx.x;   // grid is exactly 576*256 = 147456
  if (e < 16384) {                           // w1b[o][k] = bf16(w1[o][k])
    w1b[e] = (unsigned short)bf1u(w1[e]);
  } else if (e < 32768) {                    // w2b[o][k] = bf16(w2[o][k])
    int e2 = e - 16384;
    w2b[e2] = (unsigned short)bf1u(w2[e2]);
  } else if (e < 81920) {
    int e2 = e - 32768;                      // 0..49151 sampled_coor
    int bs = e2 / 3, c = e2 - bs * 3;
    int b = bs >> 11, s = bs & 2047;
    outc[e2] = coor[(b * N_ + indx[s]) * 3 + c];
  } else {
    int p = e - 81920;                       // 0..65535 coor4 pack
    const float* src = coor + (size_t)p * 3;
    coor4[p] = make_float4(src[0], src[1], src[2], 0.f);
  }
}

// ---------------- KNN: threshold-select, one query per 256-thread block -------
// Output = SET of 32 smallest keys (dist_bits<<32 | idx); order arbitrary
// (downstream max/mean/var are permutation-invariant over K).
__global__ __launch_bounds__(256, 4) void kknn(const float4* __restrict__ coor4,
                                               const int* __restrict__ indx,
                                               int* __restrict__ knn) {
  __shared__ float sdist[32 * 256];           // 32KB: dist[it][tid], conflict-free
  __shared__ float smin[128];                 // 4 waves x 32 smallest thread-mins
  __shared__ float smrg[64];                  // 2 pairwise-merged 32-lists
  __shared__ float sT;
  __shared__ unsigned long long cands[128];
  __shared__ unsigned long long ssort[128];
  __shared__ int ccnt;

  const int gid = blockIdx.x;
  const int b = gid >> 11, s = gid & 2047;
  const int tid = threadIdx.x;
  const int w = tid >> 6, lane = tid & 63;
  const float4* cb = coor4 + ((size_t)b << 13);
  const float4 q = cb[indx[s]];

  // pass 1: 32 exact distances -> LDS; track thread-min
  float dmin = 3.4e38f;
#pragma unroll 8
  for (int it = 0; it < 32; ++it) {
    const float4 c = cb[tid + (it << 8)];
    const float dx = __fsub_rn(c.x, q.x);
    const float dy = __fsub_rn(c.y, q.y);
    const float dz = __fsub_rn(c.z, q.z);
    const float d =
        __fadd_rn(__fadd_rn(__fmul_rn(dx, dx), __fmul_rn(dy, dy)), __fmul_rn(dz, dz));
    sdist[it * 256 + tid] = d;
    dmin = fminf(dmin, d);
  }
  if (tid == 0) ccnt = 0;
  if (tid < 128) cands[tid] = ~0ULL;

  // pass 2: T = exact 32nd smallest of the 256 thread-mins
  // (T >= d32: at most 31 elements lie strictly below d32, so at most 31
  //  thread-mins do; the 32nd-smallest min is >= d32.)
  float v = dmin;                             // per-wave bitonic sort (ascending)
#pragma unroll
  for (int k = 2; k <= 64; k <<= 1) {
#pragma unroll
    for (int j = k >> 1; j >= 1; j >>= 1) {
      const float o = __shfl_xor(v, j, 64);
      const bool dirAsc = ((lane & k) == 0);
      const bool lower = ((lane & j) == 0);
      const float lo = fminf(v, o), hi = fmaxf(v, o);
      v = (dirAsc == lower) ? lo : hi;
    }
  }
  if (lane < 32) smin[w * 32 + lane] = v;
  __syncthreads();
  if (w < 2) {                                // merge lists (2w, 2w+1) -> 32 smallest
    float a = (lane < 32) ? smin[w * 64 + lane] : smin[w * 64 + 32 + (63 - lane)];
#pragma unroll
    for (int j = 32; j >= 1; j >>= 1) {
      const float o = __shfl_xor(a, j, 64);
      const float lo = fminf(a, o), hi = fmaxf(a, o);
      a = ((lane & j) == 0) ? lo : hi;
    }
    if (lane < 32) smrg[w * 32 + lane] = a;
  }
  __syncthreads();
  if (w == 0) {                               // final merge -> 32nd smallest value
    float a = (lane < 32) ? smrg[lane] : smrg[32 + (63 - lane)];
#pragma unroll
    for (int j = 32; j >= 1; j >>= 1) {
      const float o = __shfl_xor(a, j, 64);
      const float lo = fminf(a, o), hi = fmaxf(a, o);
      a = ((lane & j) == 0) ? lo : hi;
    }
    if (lane == 31) sT = a;
  }
  __syncthreads();
  const float T = sT;

  // pass 3: compact candidates (dist <= T) from LDS; expected ~34-40, cap 128
#pragma unroll 8
  for (int it = 0; it < 32; ++it) {
    const float d = sdist[it * 256 + tid];
    if (d <= T) {
      const int pos = atomicAdd(&ccnt, 1);
      if (pos < 128)
        cands[pos] = ((unsigned long long)__float_as_uint(d) << 32) |
                     (unsigned int)(tid + (it << 8));
    }
  }
  __syncthreads();

  // pass 4: exact top-32 of <=128 candidates by u64 key
  if (w < 2) {                                // two parallel bitonic sort-64s
    unsigned long long kv = cands[w * 64 + lane];
#pragma unroll
    for (int k = 2; k <= 64; k <<= 1) {
#pragma unroll
      for (int j = k >> 1; j >= 1; j >>= 1) {
        const unsigned long long o = __shfl_xor(kv, j, 64);
        const bool dirAsc = ((lane & k) == 0);
        const bool lower = ((lane & j) == 0);
        const unsigned long long lo = o < kv ? o : kv;
        const unsigned long long hi = o < kv ? kv : o;
        kv = (dirAsc == lower) ? lo : hi;
      }
    }
    ssort[w * 64 + lane] = kv;
  }
  __syncthreads();
  if (w == 0) {                               // reverse-merge; lo-half holds 64 smallest
    const unsigned long long a = ssort[lane];
    const unsigned long long b2 = ssort[64 + 63 - lane];
    unsigned long long m = a < b2 ? a : b2;   // bitonic 64-seq
#pragma unroll
    for (int j = 32; j >= 1; j >>= 1) {
      const unsigned long long o = __shfl_xor(m, j, 64);
      const unsigned long long lo = o < m ? o : m;
      const unsigned long long hi = o < m ? m : o;
      m = ((lane & j) == 0) ? lo : hi;
    }
    if (lane < 32) knn[gid * 32 + lane] = (int)(unsigned int)m;
  }
}

// ---------------- phase kernels: MFMA fused GEMMs ----------------------------
// Wave w owns cols 32w..32w+31. Per lane: m = lane&31 (A row / D col), q2 = lane>>5.
// A layout: A[m=lane&31][k=q2*8+j]; B layout: B^T[n=lane&31][k=q2*8+j];
// C/D layout: col=lane&31, row=(reg&3)+8*(reg>>2)+4*q2  [m74/m101-verified].
// Layer-1 is K=128: A = [sx bf16 (k<64) | d bf16 (k>=64)], B = full w1.
// d-tile: LDS bf16, stride 68 (136B rows, uint2 ops -> 2-way aliasing = free).
template <int PHASE>
__global__ __launch_bounds__(256, 4) void kphase(
    const float* __restrict__ x, const int* __restrict__ indx,
    const int* __restrict__ knn, const float* __restrict__ b1,
    const unsigned short* __restrict__ w1b, const unsigned short* __restrict__ w2b,
    const float* __restrict__ b2, const float* __restrict__ st1,
    float* __restrict__ part, float* __restrict__ mout) {
  __shared__ __align__(16) float sx[64];
  __shared__ __align__(16) unsigned short sxb[72];   // bf16 sx (64 + pad)
  __shared__ int nbi[32];
  __shared__ __align__(16) unsigned short dls[32 * 68 + 8];
  __shared__ __align__(16) unsigned short h1[PHASE == 2 ? 32 * 136 : 8];

  const int tid = threadIdx.x;
  const int w = tid >> 6;
  const int lane = tid & 63;
  const int m = lane & 31, q2 = lane >> 5;
  const int col = (w << 5) + m;              // output channel of this lane
  const int r8 = tid >> 3, c8 = (tid & 7) * 8;  // staging map: row, col-base

  // group-invariant operands in registers
  bf8 bf1[8];
#pragma unroll
  for (int t = 0; t < 8; ++t)
    bf1[t] = *(const bf8*)&w1b[col * 128 + t * 16 + q2 * 8];
  bf8 bf2[8];
  float s1 = 0.f, t1 = 0.f, b2v = 0.f;
  if constexpr (PHASE == 2) {
#pragma unroll
    for (int t = 0; t < 8; ++t)
      bf2[t] = *(const bf8*)&w2b[col * 128 + t * 16 + q2 * 8];
    s1 = st1[col];
    t1 = st1[128 + col];
    b2v = b2[col];
  }
  (void)w2b; (void)b2; (void)st1; (void)mout;
  const float b1c = b1[col];

  float sum = 0.f, ssq = 0.f;

#pragma unroll 1
  for (int g = 0; g < GPB_; ++g) {
    const int gid = blockIdx.x * GPB_ + g;
    const int b = gid >> 11, s = gid & 2047;
    const float* xb = x + (size_t)b * (N_ * 64);
    if (tid < 64) sx[tid] = xb[(size_t)indx[s] * 64 + tid];
    if (tid >= 64 && tid < 96) nbi[tid - 64] = knn[gid * 32 + (tid - 64)];
    __syncthreads();                         // A: sx/nbi ready, prior compute done

    // stage d = x[nb[r8]] - sx as bf16 into dls (coalesced: 8 lanes per row)
    {
      const float* xrow = xb + (size_t)nbi[r8] * 64 + c8;
      const float4 xa = *(const float4*)(xrow);
      const float4 xc = *(const float4*)(xrow + 4);
      const float4 sa = *(const float4*)(sx + c8);
      const float4 sc = *(const float4*)(sx + c8 + 4);
      uint2 lo, hi;
      lo.x = bfpair(xa.x - sa.x, xa.y - sa.y);
      lo.y = bfpair(xa.z - sa.z, xa.w - sa.w);
      hi.x = bfpair(xc.x - sc.x, xc.y - sc.y);
      hi.y = bfpair(xc.z - sc.z, xc.w - sc.w);
      *(uint2*)&dls[r8 * 68 + c8] = lo;      // byte addr 136*r8+16k: 8B-aligned
      *(uint2*)&dls[r8 * 68 + c8 + 4] = hi;
    }
    if (tid < 16) {                          // pack sx -> bf16 (sx visible post-A)
      const float4 sv = *(const float4*)(sx + tid * 4);
      uint2 p;
      p.x = bfpair(sv.x, sv.y);
      p.y = bfpair(sv.z, sv.w);
      *(uint2*)&sxb[tid * 4] = p;
    }
    __syncthreads();                         // B: dls + sxb ready

    // A-frags: t<4 from sxb (k<64), t>=4 from dls (k>=64)
    bf8 af[8];
#pragma unroll
    for (int t = 0; t < 4; ++t) {
      union { bf8 v; uint2 u[2]; } fa;
      fa.u[0] = *(const uint2*)&sxb[t * 16 + q2 * 8];
      fa.u[1] = *(const uint2*)&sxb[t * 16 + q2 * 8 + 4];
      af[t] = fa.v;
    }
#pragma unroll
    for (int t = 0; t < 4; ++t) {
      union { bf8 v; uint2 u[2]; } fa;
      fa.u[0] = *(const uint2*)&dls[m * 68 + t * 16 + q2 * 8];
      fa.u[1] = *(const uint2*)&dls[m * 68 + t * 16 + q2 * 8 + 4];
      af[4 + t] = fa.v;
    }

    f32x16 acc;
#pragma unroll
    for (int r = 0; r < 16; ++r) acc[r] = b1c;
#pragma unroll
    for (int t = 0; t < 8; ++t)
      acc = __builtin_amdgcn_mfma_f32_32x32x16_bf16(af[t], bf1[t], acc, 0, 0, 0);

    if constexpr (PHASE == 1) {
#pragma unroll
      for (int r = 0; r < 16; ++r) {
        const float v = acc[r];
        sum += v;
        ssq = fmaf(v, v, ssq);
      }
    } else {
      // bn1 + relu -> h1 bf16 in LDS (C-layout scatter, row stride 136)
#pragma unroll
      for (int r = 0; r < 16; ++r) {
        const float hv = fmaxf(0.f, fmaf(acc[r], s1, t1));
        const int row = (r & 3) + ((r >> 2) << 3) + (q2 << 2);
        h1[row * 136 + col] = (unsigned short)bf1u(hv);
      }
      __syncthreads();                       // C: h1 ready

      f32x16 acc2;
#pragma unroll
      for (int r = 0; r < 16; ++r) acc2[r] = b2v;
#pragma unroll
      for (int t = 0; t < 8; ++t) {
        const bf8 a2 = *(const bf8*)&h1[m * 136 + t * 16 + q2 * 8];
        acc2 = __builtin_amdgcn_mfma_f32_32x32x16_bf16(a2, bf2[t], acc2, 0, 0, 0);
      }

      float mx = -1e30f;
#pragma unroll
      for (int r = 0; r < 16; ++r) {
        const float v = acc2[r];
        sum += v;
        ssq = fmaf(v, v, ssq);
        mx = fmaxf(mx, v);
      }
      mx = fmaxf(mx, __shfl_xor(mx, 32, 64));
      if (lane < 32) mout[(size_t)gid * 128 + col] = mx;
    }
  }

  // channel partials: each channel owned by exactly one wave
  sum += __shfl_xor(sum, 32, 64);
  ssq += __shfl_xor(ssq, 32, 64);
  if (lane < 32) {
    part[blockIdx.x * 256 + col] = sum;
    part[blockIdx.x * 256 + 128 + col] = ssq;
  }
}

// ---------------- stats finalize (double precision) --------------------------
__global__ __launch_bounds__(1024) void kreduce(const float* __restrict__ part,
                                                const float* __restrict__ gam,
                                                const float* __restrict__ bet,
                                                float* __restrict__ st) {
  __shared__ double redd[4][256];
  const int tid = threadIdx.x;
  const int c = tid & 255, pq = tid >> 8;
  double acc = 0.0;
  for (int row = pq; row < 2048; row += 4) acc += (double)part[row * 256 + c];
  redd[pq][c] = acc;
  __syncthreads();
  if (tid < 256) redd[0][tid] = redd[0][tid] + redd[1][tid] + redd[2][tid] + redd[3][tid];
  __syncthreads();
  if (tid < 128) {
    const double Sv = redd[0][tid], SSv = redd[0][128 + tid];
    const double cnt = 524288.0;                 // B*S*K
    const double mean = Sv / cnt;
    const double var = SSv / cnt - mean * mean;
    const double scale = (double)gam[tid] / sqrt(var + 1e-5);
    st[tid] = (float)scale;
    st[128 + tid] = (float)((double)bet[tid] - mean * scale);
  }
}

// ---------------- final: out = relu(scale2 * max_k(y2) + shift2) -------------
__global__ __launch_bounds__(256) void kout(const float* __restrict__ m,
                                            const float* __restrict__ st2,
                                            float* __restrict__ out) {
  const int e4 = blockIdx.x * 256 + threadIdx.x;  // 524288 float4s
  const int o0 = (e4 & 31) * 4;
  const float4 v = ((const float4*)m)[e4];
  const float4 sc = *(const float4*)&st2[o0];
  const float4 sh = *(const float4*)&st2[128 + o0];
  float4 r;
  r.x = fmaxf(0.f, fmaf(v.x, sc.x, sh.x));
  r.y = fmaxf(0.f, fmaf(v.y, sc.y, sh.y));
  r.z = fmaxf(0.f, fmaf(v.z, sc.z, sh.z));
  r.w = fmaxf(0.f, fmaf(v.w, sc.w, sh.w));
  ((float4*)out)[e4] = r;
}

extern "C" void kernel_launch(void* const* d_in, const int* in_sizes, int n_in,
                              void* d_out, int out_size, void* d_ws, size_t ws_size,
                              hipStream_t stream) {
  (void)in_sizes; (void)n_in; (void)out_size; (void)ws_size;
  const float* x    = (const float*)d_in[0];
  const float* coor = (const float*)d_in[1];
  const int*   indx = (const int*)d_in[2];
  const float* w1   = (const float*)d_in[3];
  const float* b1   = (const float*)d_in[4];
  const float* g1   = (const float*)d_in[5];
  const float* be1  = (const float*)d_in[6];
  const float* w2   = (const float*)d_in[7];
  const float* b2   = (const float*)d_in[8];
  const float* g2   = (const float*)d_in[9];
  const float* be2  = (const float*)d_in[10];
  float* out = (float*)d_out;

  char* ws = (char*)d_ws;
  int*            knn   = (int*)(ws + 0);
  float*          mbuf  = (float*)(ws + 2097152);
  float*          part1 = (float*)(ws + 10485760);
  float4*         coor4 = (float4*)(ws + 10485760); // aliases part1 (disjoint lifetime)
  float*          part2 = (float*)(ws + 12582912);
  unsigned short* w1b   = (unsigned short*)(ws + 14680064);
  unsigned short* w2b   = (unsigned short*)(ws + 14712832);
  float*          st1   = (float*)(ws + 14745600);
  float*          st2   = (float*)(ws + 14746624);

  float* outc = out + 2097152;   // sampled_coor region of d_out

  kprep<<<576, 256, 0, stream>>>(w1, w2, coor, indx, w1b, w2b, outc, coor4);
  kknn<<<16384, 256, 0, stream>>>(coor4, indx, knn);
  kphase<1><<<2048, 256, 0, stream>>>(x, indx, knn, b1, w1b, w2b, b2, nullptr,
                                      part1, nullptr);
  kreduce<<<1, 1024, 0, stream>>>(part1, g1, be1, st1);
  kphase<2><<<2048, 256, 0, stream>>>(x, indx, knn, b1, w1b, w2b, b2, st1,
                                      part2, mbuf);
  kreduce<<<1, 1024, 0, stream>>>(part2, g2, be2, st2);
  kout<<<2048, 256, 0, stream>>>(mbuf, st2, out);
}

// Round 10
// 609.482 us; speedup vs baseline: 5.7639x; 1.0020x over previous
//
#include <hip/hip_runtime.h>
#include <stdint.h>

// sample_and_group: B=8 N=8192 C=64 S=2048 K=32 OUT=128
// out = (out[8,2048,128], sampled_coor[8,2048,3]) concatenated in d_out (float32).
//
// R9 fix: R8 proved phases are NOT VALU/chain/barrier-bound (deleting all of it
// was neutral). New theory: gather-latency-bound. Two latency plays, numerics
// bit-identical: (1) XCD-aware mapping — block handles batch b = blockIdx&7, so
// each XCD's L2 holds ONE 2MB x-slice (gathers become L2 hits, not L3/HBM);
// (2) depth-1 prefetch of indx[s] -> sx row -> knn row for group g+1 during
// group g's staging/MFMA (nbi LDS deleted; per-thread row-index prefetch).
//
// Workspace layout (bytes):
//   [0,2MB)        knn indices  int32[16384*32]
//   [2MB,10MB)     m = max_k y2 f32[16384*128]
//   [10MB,11MB)    coor4 float4[8*8192]   (ALIASES part1; kknn-only lifetime)
//   [10MB,12MB)    partials1    f32[2048*256]
//   [12MB,14MB)    partials2    f32[2048*256]
//   [14MB,+32KB)   w1b  bf16 [o][k=0..127]
//   [..,+32KB)     w2b  bf16 [o][k=0..127]
//   [..,+1KB)      stats1 (scale[128], shift[128])
//   [..,+1KB)      stats2

#define N_    8192
#define GPB_  8       // groups per block in phase kernels

typedef __attribute__((ext_vector_type(8))) short bf8;
typedef __attribute__((ext_vector_type(16))) float f32x16;

__device__ __forceinline__ unsigned int bf1u(float f) {   // RNE fp32->bf16 bits
  unsigned int u = __float_as_uint(f);
  return (u + 0x7fffu + ((u >> 16) & 1u)) >> 16;
}
__device__ __forceinline__ unsigned int bfpair(float lo, float hi) {
  return bf1u(lo) | (bf1u(hi) << 16);
}

// ---------------- prep: weight layouts + coor4 pack + sampled_coor ------------
__global__ __launch_bounds__(256) void kprep(const float* __restrict__ w1,
                                             const float* __restrict__ w2,
                                             const float* __restrict__ coor,
                                             const int* __restrict__ indx,
                                             unsigned short* __restrict__ w1b,
                                             unsigned short* __restrict__ w2b,
                                             float* __restrict__ outc,
                                             float4* __restrict__ coor4) {
  int e = blockIdx.x * 256 + threadIdx.x;   // grid is exactly 576*256 = 147456
  if (e < 16384) {                           // w1b[o][k] = bf16(w1[o][k])
    w1b[e] = (unsigned short)bf1u(w1[e]);
  } else if (e < 32768) {                    // w2b[o][k] = bf16(w2[o][k])
    int e2 = e - 16384;
    w2b[e2] = (unsigned short)bf1u(w2[e2]);
  } else if (e < 81920) {
    int e2 = e - 32768;                      // 0..49151 sampled_coor
    int bs = e2 / 3, c = e2 - bs * 3;
    int b = bs >> 11, s = bs & 2047;
    outc[e2] = coor[(b * N_ + indx[s]) * 3 + c];
  } else {
    int p = e - 81920;                       // 0..65535 coor4 pack
    const float* src = coor + (size_t)p * 3;
    coor4[p] = make_float4(src[0], src[1], src[2], 0.f);
  }
}

// ---------------- KNN: threshold-select, one query per 256-thread block -------
// Output = SET of 32 smallest keys (dist_bits<<32 | idx); order arbitrary
// (downstream max/mean/var are permutation-invariant over K).
__global__ __launch_bounds__(256, 4) void kknn(const float4* __restrict__ coor4,
                                               const int* __restrict__ indx,
                                               int* __restrict__ knn) {
  __shared__ float sdist[32 * 256];           // 32KB: dist[it][tid], conflict-free
  __shared__ float smin[128];                 // 4 waves x 32 smallest thread-mins
  __shared__ float smrg[64];                  // 2 pairwise-merged 32-lists
  __shared__ float sT;
  __shared__ unsigned long long cands[128];
  __shared__ unsigned long long ssort[128];
  __shared__ int ccnt;

  const int gid = blockIdx.x;
  const int b = gid >> 11, s = gid & 2047;
  const int tid = threadIdx.x;
  const int w = tid >> 6, lane = tid & 63;
  const float4* cb = coor4 + ((size_t)b << 13);
  const float4 q = cb[indx[s]];

  // pass 1: 32 exact distances -> LDS; track thread-min
  float dmin = 3.4e38f;
#pragma unroll 8
  for (int it = 0; it < 32; ++it) {
    const float4 c = cb[tid + (it << 8)];
    const float dx = __fsub_rn(c.x, q.x);
    const float dy = __fsub_rn(c.y, q.y);
    const float dz = __fsub_rn(c.z, q.z);
    const float d =
        __fadd_rn(__fadd_rn(__fmul_rn(dx, dx), __fmul_rn(dy, dy)), __fmul_rn(dz, dz));
    sdist[it * 256 + tid] = d;
    dmin = fminf(dmin, d);
  }
  if (tid == 0) ccnt = 0;
  if (tid < 128) cands[tid] = ~0ULL;

  // pass 2: T = exact 32nd smallest of the 256 thread-mins
  // (T >= d32: at most 31 elements lie strictly below d32, so at most 31
  //  thread-mins do; the 32nd-smallest min is >= d32.)
  float v = dmin;                             // per-wave bitonic sort (ascending)
#pragma unroll
  for (int k = 2; k <= 64; k <<= 1) {
#pragma unroll
    for (int j = k >> 1; j >= 1; j >>= 1) {
      const float o = __shfl_xor(v, j, 64);
      const bool dirAsc = ((lane & k) == 0);
      const bool lower = ((lane & j) == 0);
      const float lo = fminf(v, o), hi = fmaxf(v, o);
      v = (dirAsc == lower) ? lo : hi;
    }
  }
  if (lane < 32) smin[w * 32 + lane] = v;
  __syncthreads();
  if (w < 2) {                                // merge lists (2w, 2w+1) -> 32 smallest
    float a = (lane < 32) ? smin[w * 64 + lane] : smin[w * 64 + 32 + (63 - lane)];
#pragma unroll
    for (int j = 32; j >= 1; j >>= 1) {
      const float o = __shfl_xor(a, j, 64);
      const float lo = fminf(a, o), hi = fmaxf(a, o);
      a = ((lane & j) == 0) ? lo : hi;
    }
    if (lane < 32) smrg[w * 32 + lane] = a;
  }
  __syncthreads();
  if (w == 0) {                               // final merge -> 32nd smallest value
    float a = (lane < 32) ? smrg[lane] : smrg[32 + (63 - lane)];
#pragma unroll
    for (int j = 32; j >= 1; j >>= 1) {
      const float o = __shfl_xor(a, j, 64);
      const float lo = fminf(a, o), hi = fmaxf(a, o);
      a = ((lane & j) == 0) ? lo : hi;
    }
    if (lane == 31) sT = a;
  }
  __syncthreads();
  const float T = sT;

  // pass 3: compact candidates (dist <= T) from LDS; expected ~34-40, cap 128
#pragma unroll 8
  for (int it = 0; it < 32; ++it) {
    const float d = sdist[it * 256 + tid];
    if (d <= T) {
      const int pos = atomicAdd(&ccnt, 1);
      if (pos < 128)
        cands[pos] = ((unsigned long long)__float_as_uint(d) << 32) |
                     (unsigned int)(tid + (it << 8));
    }
  }
  __syncthreads();

  // pass 4: exact top-32 of <=128 candidates by u64 key
  if (w < 2) {                                // two parallel bitonic sort-64s
    unsigned long long kv = cands[w * 64 + lane];
#pragma unroll
    for (int k = 2; k <= 64; k <<= 1) {
#pragma unroll
      for (int j = k >> 1; j >= 1; j >>= 1) {
        const unsigned long long o = __shfl_xor(kv, j, 64);
        const bool dirAsc = ((lane & k) == 0);
        const bool lower = ((lane & j) == 0);
        const unsigned long long lo = o < kv ? o : kv;
        const unsigned long long hi = o < kv ? kv : o;
        kv = (dirAsc == lower) ? lo : hi;
      }
    }
    ssort[w * 64 + lane] = kv;
  }
  __syncthreads();
  if (w == 0) {                               // reverse-merge; lo-half holds 64 smallest
    const unsigned long long a = ssort[lane];
    const unsigned long long b2 = ssort[64 + 63 - lane];
    unsigned long long m = a < b2 ? a : b2;   // bitonic 64-seq
#pragma unroll
    for (int j = 32; j >= 1; j >>= 1) {
      const unsigned long long o = __shfl_xor(m, j, 64);
      const unsigned long long lo = o < m ? o : m;
      const unsigned long long hi = o < m ? m : o;
      m = ((lane & j) == 0) ? lo : hi;
    }
    if (lane < 32) knn[gid * 32 + lane] = (int)(unsigned int)m;
  }
}

// ---------------- phase kernels: MFMA fused GEMMs ----------------------------
// Wave w owns cols 32w..32w+31. Per lane: m = lane&31 (A row / D col), q2 = lane>>5.
// A layout: A[m=lane&31][k=q2*8+j]; B layout: B^T[n=lane&31][k=q2*8+j];
// C/D layout: col=lane&31, row=(reg&3)+8*(reg>>2)+4*q2  [m74/m101-verified].
// Layer-1 is K=128: A = [sx bf16 (k<64) | d bf16 (k>=64)], B = full w1.
// XCD map: batch = blockIdx&7 (one 2MB x-slice per XCD L2); depth-1 prefetch
// of indx/sx-row/knn-row for group g+1 overlaps group g's staging+MFMA.
template <int PHASE>
__global__ __launch_bounds__(256, 4) void kphase(
    const float* __restrict__ x, const int* __restrict__ indx,
    const int* __restrict__ knn, const float* __restrict__ b1,
    const unsigned short* __restrict__ w1b, const unsigned short* __restrict__ w2b,
    const float* __restrict__ b2, const float* __restrict__ st1,
    float* __restrict__ part, float* __restrict__ mout) {
  __shared__ __align__(16) float sx[64];
  __shared__ __align__(16) unsigned short sxb[72];   // bf16 sx (64 + pad)
  __shared__ __align__(16) unsigned short dls[32 * 68 + 8];
  __shared__ __align__(16) unsigned short h1[PHASE == 2 ? 32 * 136 : 8];

  const int tid = threadIdx.x;
  const int w = tid >> 6;
  const int lane = tid & 63;
  const int m = lane & 31, q2 = lane >> 5;
  const int col = (w << 5) + m;              // output channel of this lane
  const int r8 = tid >> 3, c8 = (tid & 7) * 8;  // staging map: row, col-base

  const int bb = blockIdx.x & 7;             // batch == target XCD
  const int jj = blockIdx.x >> 3;            // 0..255 chunk within batch
  const float* xb = x + (size_t)bb * (N_ * 64);
  const int gidbase = (bb << 11) + jj * GPB_;

  // group-invariant operands in registers
  bf8 bf1[8];
#pragma unroll
  for (int t = 0; t < 8; ++t)
    bf1[t] = *(const bf8*)&w1b[col * 128 + t * 16 + q2 * 8];
  bf8 bf2[8];
  float s1 = 0.f, t1 = 0.f, b2v = 0.f;
  if constexpr (PHASE == 2) {
#pragma unroll
    for (int t = 0; t < 8; ++t)
      bf2[t] = *(const bf8*)&w2b[col * 128 + t * 16 + q2 * 8];
    s1 = st1[col];
    t1 = st1[128 + col];
    b2v = b2[col];
  }
  (void)w2b; (void)b2; (void)st1; (void)mout;
  const float b1c = b1[col];

  float sum = 0.f, ssq = 0.f;

  // depth-1 prefetch for g = 0
  int idxp = indx[jj * GPB_];
  float sxv = (tid < 64) ? xb[(size_t)idxp * 64 + tid] : 0.f;
  int nbr = knn[(size_t)gidbase * 32 + r8];

#pragma unroll 1
  for (int g = 0; g < GPB_; ++g) {
    const int gid = gidbase + g;
    if (tid < 64) sx[tid] = sxv;
    __syncthreads();                         // A: sx visible; prior dls reads done

    // stage d = x[nbr] - sx as bf16 into dls (coalesced: 8 lanes per row)
    {
      const float* xrow = xb + (size_t)nbr * 64 + c8;
      const float4 xa = *(const float4*)(xrow);
      const float4 xc = *(const float4*)(xrow + 4);
      const float4 sa = *(const float4*)(sx + c8);
      const float4 sc = *(const float4*)(sx + c8 + 4);
      uint2 lo, hi;
      lo.x = bfpair(xa.x - sa.x, xa.y - sa.y);
      lo.y = bfpair(xa.z - sa.z, xa.w - sa.w);
      hi.x = bfpair(xc.x - sc.x, xc.y - sc.y);
      hi.y = bfpair(xc.z - sc.z, xc.w - sc.w);
      *(uint2*)&dls[r8 * 68 + c8] = lo;      // byte addr 136*r8+16k: 8B-aligned
      *(uint2*)&dls[r8 * 68 + c8 + 4] = hi;
    }
    if (tid < 16) {                          // pack sx -> bf16 (post-A)
      const float4 sv = *(const float4*)(sx + tid * 4);
      uint2 p;
      p.x = bfpair(sv.x, sv.y);
      p.y = bfpair(sv.z, sv.w);
      *(uint2*)&sxb[tid * 4] = p;
    }

    // prefetch g+1 chain (overlaps this group's MFMA; independent of LDS)
    if (g + 1 < GPB_) {
      const int s1n = jj * GPB_ + g + 1;
      const int idx1 = indx[s1n];
      sxv = (tid < 64) ? xb[(size_t)idx1 * 64 + tid] : 0.f;
      nbr = knn[(size_t)(gid + 1) * 32 + r8];
    }
    __syncthreads();                         // B: dls + sxb ready

    // A-frags: t<4 from sxb (k<64), t>=4 from dls (k>=64)
    bf8 af[8];
#pragma unroll
    for (int t = 0; t < 4; ++t) {
      union { bf8 v; uint2 u[2]; } fa;
      fa.u[0] = *(const uint2*)&sxb[t * 16 + q2 * 8];
      fa.u[1] = *(const uint2*)&sxb[t * 16 + q2 * 8 + 4];
      af[t] = fa.v;
    }
#pragma unroll
    for (int t = 0; t < 4; ++t) {
      union { bf8 v; uint2 u[2]; } fa;
      fa.u[0] = *(const uint2*)&dls[m * 68 + t * 16 + q2 * 8];
      fa.u[1] = *(const uint2*)&dls[m * 68 + t * 16 + q2 * 8 + 4];
      af[4 + t] = fa.v;
    }

    f32x16 acc;
#pragma unroll
    for (int r = 0; r < 16; ++r) acc[r] = b1c;
#pragma unroll
    for (int t = 0; t < 8; ++t)
      acc = __builtin_amdgcn_mfma_f32_32x32x16_bf16(af[t], bf1[t], acc, 0, 0, 0);

    if constexpr (PHASE == 1) {
#pragma unroll
      for (int r = 0; r < 16; ++r) {
        const float v = acc[r];
        sum += v;
        ssq = fmaf(v, v, ssq);
      }
    } else {
      // bn1 + relu -> h1 bf16 in LDS (C-layout scatter, row stride 136)
#pragma unroll
      for (int r = 0; r < 16; ++r) {
        const float hv = fmaxf(0.f, fmaf(acc[r], s1, t1));
        const int row = (r & 3) + ((r >> 2) << 3) + (q2 << 2);
        h1[row * 136 + col] = (unsigned short)bf1u(hv);
      }
      __syncthreads();                       // C: h1 ready

      f32x16 acc2;
#pragma unroll
      for (int r = 0; r < 16; ++r) acc2[r] = b2v;
#pragma unroll
      for (int t = 0; t < 8; ++t) {
        const bf8 a2 = *(const bf8*)&h1[m * 136 + t * 16 + q2 * 8];
        acc2 = __builtin_amdgcn_mfma_f32_32x32x16_bf16(a2, bf2[t], acc2, 0, 0, 0);
      }

      float mx = -1e30f;
#pragma unroll
      for (int r = 0; r < 16; ++r) {
        const float v = acc2[r];
        sum += v;
        ssq = fmaf(v, v, ssq);
        mx = fmaxf(mx, v);
      }
      mx = fmaxf(mx, __shfl_xor(mx, 32, 64));
      if (lane < 32) mout[(size_t)gid * 128 + col] = mx;
    }
  }

  // channel partials: each channel owned by exactly one wave
  sum += __shfl_xor(sum, 32, 64);
  ssq += __shfl_xor(ssq, 32, 64);
  if (lane < 32) {
    part[blockIdx.x * 256 + col] = sum;
    part[blockIdx.x * 256 + 128 + col] = ssq;
  }
}

// ---------------- stats finalize (double precision) --------------------------
__global__ __launch_bounds__(1024) void kreduce(const float* __restrict__ part,
                                                const float* __restrict__ gam,
                                                const float* __restrict__ bet,
                                                float* __restrict__ st) {
  __shared__ double redd[4][256];
  const int tid = threadIdx.x;
  const int c = tid & 255, pq = tid >> 8;
  double acc = 0.0;
  for (int row = pq; row < 2048; row += 4) acc += (double)part[row * 256 + c];
  redd[pq][c] = acc;
  __syncthreads();
  if (tid < 256) redd[0][tid] = redd[0][tid] + redd[1][tid] + redd[2][tid] + redd[3][tid];
  __syncthreads();
  if (tid < 128) {
    const double Sv = redd[0][tid], SSv = redd[0][128 + tid];
    const double cnt = 524288.0;                 // B*S*K
    const double mean = Sv / cnt;
    const double var = SSv / cnt - mean * mean;
    const double scale = (double)gam[tid] / sqrt(var + 1e-5);
    st[tid] = (float)scale;
    st[128 + tid] = (float)((double)bet[tid] - mean * scale);
  }
}

// ---------------- final: out = relu(scale2 * max_k(y2) + shift2) -------------
__global__ __launch_bounds__(256) void kout(const float* __restrict__ m,
                                            const float* __restrict__ st2,
                                            float* __restrict__ out) {
  const int e4 = blockIdx.x * 256 + threadIdx.x;  // 524288 float4s
  const int o0 = (e4 & 31) * 4;
  const float4 v = ((const float4*)m)[e4];
  const float4 sc = *(const float4*)&st2[o0];
  const float4 sh = *(const float4*)&st2[128 + o0];
  float4 r;
  r.x = fmaxf(0.f, fmaf(v.x, sc.x, sh.x));
  r.y = fmaxf(0.f, fmaf(v.y, sc.y, sh.y));
  r.z = fmaxf(0.f, fmaf(v.z, sc.z, sh.z));
  r.w = fmaxf(0.f, fmaf(v.w, sc.w, sh.w));
  ((float4*)out)[e4] = r;
}

extern "C" void kernel_launch(void* const* d_in, const int* in_sizes, int n_in,
                              void* d_out, int out_size, void* d_ws, size_t ws_size,
                              hipStream_t stream) {
  (void)in_sizes; (void)n_in; (void)out_size; (void)ws_size;
  const float* x    = (const float*)d_in[0];
  const float* coor = (const float*)d_in[1];
  const int*   indx = (const int*)d_in[2];
  const float* w1   = (const float*)d_in[3];
  const float* b1   = (const float*)d_in[4];
  const float* g1   = (const float*)d_in[5];
  const float* be1  = (const float*)d_in[6];
  const float* w2   = (const float*)d_in[7];
  const float* b2   = (const float*)d_in[8];
  const float* g2   = (const float*)d_in[9];
  const float* be2  = (const float*)d_in[10];
  float* out = (float*)d_out;

  char* ws = (char*)d_ws;
  int*            knn   = (int*)(ws + 0);
  float*          mbuf  = (float*)(ws + 2097152);
  float*          part1 = (float*)(ws + 10485760);
  float4*         coor4 = (float4*)(ws + 10485760); // aliases part1 (disjoint lifetime)
  float*          part2 = (float*)(ws + 12582912);
  unsigned short* w1b   = (unsigned short*)(ws + 14680064);
  unsigned short* w2b   = (unsigned short*)(ws + 14712832);
  float*          st1   = (float*)(ws + 14745600);
  float*          st2   = (float*)(ws + 14746624);

  float* outc = out + 2097152;   // sampled_coor region of d_out

  kprep<<<576, 256, 0, stream>>>(w1, w2, coor, indx, w1b, w2b, outc, coor4);
  kknn<<<16384, 256, 0, stream>>>(coor4, indx, knn);
  kphase<1><<<2048, 256, 0, stream>>>(x, indx, knn, b1, w1b, w2b, b2, nullptr,
                                      part1, nullptr);
  kreduce<<<1, 1024, 0, stream>>>(part1, g1, be1, st1);
  kphase<2><<<2048, 256, 0, stream>>>(x, indx, knn, b1, w1b, w2b, b2, st1,
                                      part2, mbuf);
  kreduce<<<1, 1024, 0, stream>>>(part2, g2, be2, st2);
  kout<<<2048, 256, 0, stream>>>(mbuf, st2, out);
}

// Round 11
// 334.545 us; speedup vs baseline: 10.5008x; 1.8218x over previous
//
#include <hip/hip_runtime.h>
#include <stdint.h>

// sample_and_group: B=8 N=8192 C=64 S=2048 K=32 OUT=128
// out = (out[8,2048,128], sampled_coor[8,2048,3]) concatenated in d_out (float32).
//
// R10 fix: accounting showed ~459us not in top-5 while phase critical-path
// arithmetic is ~10-25us -> prime suspect is kreduce: a SINGLE-BLOCK kernel
// reading 2MB of cross-XCD partials with a thin pipeline, ~100us x2 launches.
// Replaced by two-stage grid-parallel reduce: kred1 (64 blocks, f64 partial
// sums of 32 rows x 256 ch) + kred2 (1 block, 64-row f64 finish + stats).
// Everything else byte-identical to R10 (kknn/phases untouched).
//
// Workspace layout (bytes):
//   [0,2MB)        knn indices  int32[16384*32]
//   [2MB,10MB)     m = max_k y2 f32[16384*128]
//   [10MB,11MB)    coor4 float4[8*8192]   (ALIASES part1; kknn-only lifetime)
//   [10MB,12MB)    partials1    f32[2048*256]
//   [12MB,14MB)    partials2    f32[2048*256]
//   [14MB,+32KB)   w1b  bf16 [o][k=0..127]
//   [..,+32KB)     w2b  bf16 [o][k=0..127]
//   [..,+1KB)      stats1 (scale[128], shift[128])
//   [..,+1KB)      stats2
//   [..,+128KB)    dbuf f64[64*256] (reduce stage-1 output)

#define N_    8192
#define GPB_  8       // groups per block in phase kernels

typedef __attribute__((ext_vector_type(8))) short bf8;
typedef __attribute__((ext_vector_type(16))) float f32x16;

__device__ __forceinline__ unsigned int bf1u(float f) {   // RNE fp32->bf16 bits
  unsigned int u = __float_as_uint(f);
  return (u + 0x7fffu + ((u >> 16) & 1u)) >> 16;
}
__device__ __forceinline__ unsigned int bfpair(float lo, float hi) {
  return bf1u(lo) | (bf1u(hi) << 16);
}

// ---------------- prep: weight layouts + coor4 pack + sampled_coor ------------
__global__ __launch_bounds__(256) void kprep(const float* __restrict__ w1,
                                             const float* __restrict__ w2,
                                             const float* __restrict__ coor,
                                             const int* __restrict__ indx,
                                             unsigned short* __restrict__ w1b,
                                             unsigned short* __restrict__ w2b,
                                             float* __restrict__ outc,
                                             float4* __restrict__ coor4) {
  int e = blockIdx.x * 256 + threadIdx.x;   // grid is exactly 576*256 = 147456
  if (e < 16384) {                           // w1b[o][k] = bf16(w1[o][k])
    w1b[e] = (unsigned short)bf1u(w1[e]);
  } else if (e < 32768) {                    // w2b[o][k] = bf16(w2[o][k])
    int e2 = e - 16384;
    w2b[e2] = (unsigned short)bf1u(w2[e2]);
  } else if (e < 81920) {
    int e2 = e - 32768;                      // 0..49151 sampled_coor
    int bs = e2 / 3, c = e2 - bs * 3;
    int b = bs >> 11, s = bs & 2047;
    outc[e2] = coor[(b * N_ + indx[s]) * 3 + c];
  } else {
    int p = e - 81920;                       // 0..65535 coor4 pack
    const float* src = coor + (size_t)p * 3;
    coor4[p] = make_float4(src[0], src[1], src[2], 0.f);
  }
}

// ---------------- KNN: threshold-select, one query per 256-thread block -------
// Output = SET of 32 smallest keys (dist_bits<<32 | idx); order arbitrary
// (downstream max/mean/var are permutation-invariant over K).
__global__ __launch_bounds__(256, 4) void kknn(const float4* __restrict__ coor4,
                                               const int* __restrict__ indx,
                                               int* __restrict__ knn) {
  __shared__ float sdist[32 * 256];           // 32KB: dist[it][tid], conflict-free
  __shared__ float smin[128];                 // 4 waves x 32 smallest thread-mins
  __shared__ float smrg[64];                  // 2 pairwise-merged 32-lists
  __shared__ float sT;
  __shared__ unsigned long long cands[128];
  __shared__ unsigned long long ssort[128];
  __shared__ int ccnt;

  const int gid = blockIdx.x;
  const int b = gid >> 11, s = gid & 2047;
  const int tid = threadIdx.x;
  const int w = tid >> 6, lane = tid & 63;
  const float4* cb = coor4 + ((size_t)b << 13);
  const float4 q = cb[indx[s]];

  // pass 1: 32 exact distances -> LDS; track thread-min
  float dmin = 3.4e38f;
#pragma unroll 8
  for (int it = 0; it < 32; ++it) {
    const float4 c = cb[tid + (it << 8)];
    const float dx = __fsub_rn(c.x, q.x);
    const float dy = __fsub_rn(c.y, q.y);
    const float dz = __fsub_rn(c.z, q.z);
    const float d =
        __fadd_rn(__fadd_rn(__fmul_rn(dx, dx), __fmul_rn(dy, dy)), __fmul_rn(dz, dz));
    sdist[it * 256 + tid] = d;
    dmin = fminf(dmin, d);
  }
  if (tid == 0) ccnt = 0;
  if (tid < 128) cands[tid] = ~0ULL;

  // pass 2: T = exact 32nd smallest of the 256 thread-mins
  // (T >= d32: at most 31 elements lie strictly below d32, so at most 31
  //  thread-mins do; the 32nd-smallest min is >= d32.)
  float v = dmin;                             // per-wave bitonic sort (ascending)
#pragma unroll
  for (int k = 2; k <= 64; k <<= 1) {
#pragma unroll
    for (int j = k >> 1; j >= 1; j >>= 1) {
      const float o = __shfl_xor(v, j, 64);
      const bool dirAsc = ((lane & k) == 0);
      const bool lower = ((lane & j) == 0);
      const float lo = fminf(v, o), hi = fmaxf(v, o);
      v = (dirAsc == lower) ? lo : hi;
    }
  }
  if (lane < 32) smin[w * 32 + lane] = v;
  __syncthreads();
  if (w < 2) {                                // merge lists (2w, 2w+1) -> 32 smallest
    float a = (lane < 32) ? smin[w * 64 + lane] : smin[w * 64 + 32 + (63 - lane)];
#pragma unroll
    for (int j = 32; j >= 1; j >>= 1) {
      const float o = __shfl_xor(a, j, 64);
      const float lo = fminf(a, o), hi = fmaxf(a, o);
      a = ((lane & j) == 0) ? lo : hi;
    }
    if (lane < 32) smrg[w * 32 + lane] = a;
  }
  __syncthreads();
  if (w == 0) {                               // final merge -> 32nd smallest value
    float a = (lane < 32) ? smrg[lane] : smrg[32 + (63 - lane)];
#pragma unroll
    for (int j = 32; j >= 1; j >>= 1) {
      const float o = __shfl_xor(a, j, 64);
      const float lo = fminf(a, o), hi = fmaxf(a, o);
      a = ((lane & j) == 0) ? lo : hi;
    }
    if (lane == 31) sT = a;
  }
  __syncthreads();
  const float T = sT;

  // pass 3: compact candidates (dist <= T) from LDS; expected ~34-40, cap 128
#pragma unroll 8
  for (int it = 0; it < 32; ++it) {
    const float d = sdist[it * 256 + tid];
    if (d <= T) {
      const int pos = atomicAdd(&ccnt, 1);
      if (pos < 128)
        cands[pos] = ((unsigned long long)__float_as_uint(d) << 32) |
                     (unsigned int)(tid + (it << 8));
    }
  }
  __syncthreads();

  // pass 4: exact top-32 of <=128 candidates by u64 key
  if (w < 2) {                                // two parallel bitonic sort-64s
    unsigned long long kv = cands[w * 64 + lane];
#pragma unroll
    for (int k = 2; k <= 64; k <<= 1) {
#pragma unroll
      for (int j = k >> 1; j >= 1; j >>= 1) {
        const unsigned long long o = __shfl_xor(kv, j, 64);
        const bool dirAsc = ((lane & k) == 0);
        const bool lower = ((lane & j) == 0);
        const unsigned long long lo = o < kv ? o : kv;
        const unsigned long long hi = o < kv ? kv : o;
        kv = (dirAsc == lower) ? lo : hi;
      }
    }
    ssort[w * 64 + lane] = kv;
  }
  __syncthreads();
  if (w == 0) {                               // reverse-merge; lo-half holds 64 smallest
    const unsigned long long a = ssort[lane];
    const unsigned long long b2 = ssort[64 + 63 - lane];
    unsigned long long m = a < b2 ? a : b2;   // bitonic 64-seq
#pragma unroll
    for (int j = 32; j >= 1; j >>= 1) {
      const unsigned long long o = __shfl_xor(m, j, 64);
      const unsigned long long lo = o < m ? o : m;
      const unsigned long long hi = o < m ? m : o;
      m = ((lane & j) == 0) ? lo : hi;
    }
    if (lane < 32) knn[gid * 32 + lane] = (int)(unsigned int)m;
  }
}

// ---------------- phase kernels: MFMA fused GEMMs ----------------------------
// Wave w owns cols 32w..32w+31. Per lane: m = lane&31 (A row / D col), q2 = lane>>5.
// A layout: A[m=lane&31][k=q2*8+j]; B layout: B^T[n=lane&31][k=q2*8+j];
// C/D layout: col=lane&31, row=(reg&3)+8*(reg>>2)+4*q2  [m74/m101-verified].
// Layer-1 is K=128: A = [sx bf16 (k<64) | d bf16 (k>=64)], B = full w1.
// XCD map: batch = blockIdx&7 (one 2MB x-slice per XCD L2); depth-1 prefetch
// of indx/sx-row/knn-row for group g+1 overlaps group g's staging+MFMA.
template <int PHASE>
__global__ __launch_bounds__(256, 4) void kphase(
    const float* __restrict__ x, const int* __restrict__ indx,
    const int* __restrict__ knn, const float* __restrict__ b1,
    const unsigned short* __restrict__ w1b, const unsigned short* __restrict__ w2b,
    const float* __restrict__ b2, const float* __restrict__ st1,
    float* __restrict__ part, float* __restrict__ mout) {
  __shared__ __align__(16) float sx[64];
  __shared__ __align__(16) unsigned short sxb[72];   // bf16 sx (64 + pad)
  __shared__ __align__(16) unsigned short dls[32 * 68 + 8];
  __shared__ __align__(16) unsigned short h1[PHASE == 2 ? 32 * 136 : 8];

  const int tid = threadIdx.x;
  const int w = tid >> 6;
  const int lane = tid & 63;
  const int m = lane & 31, q2 = lane >> 5;
  const int col = (w << 5) + m;              // output channel of this lane
  const int r8 = tid >> 3, c8 = (tid & 7) * 8;  // staging map: row, col-base

  const int bb = blockIdx.x & 7;             // batch == target XCD
  const int jj = blockIdx.x >> 3;            // 0..255 chunk within batch
  const float* xb = x + (size_t)bb * (N_ * 64);
  const int gidbase = (bb << 11) + jj * GPB_;

  // group-invariant operands in registers
  bf8 bf1[8];
#pragma unroll
  for (int t = 0; t < 8; ++t)
    bf1[t] = *(const bf8*)&w1b[col * 128 + t * 16 + q2 * 8];
  bf8 bf2[8];
  float s1 = 0.f, t1 = 0.f, b2v = 0.f;
  if constexpr (PHASE == 2) {
#pragma unroll
    for (int t = 0; t < 8; ++t)
      bf2[t] = *(const bf8*)&w2b[col * 128 + t * 16 + q2 * 8];
    s1 = st1[col];
    t1 = st1[128 + col];
    b2v = b2[col];
  }
  (void)w2b; (void)b2; (void)st1; (void)mout;
  const float b1c = b1[col];

  float sum = 0.f, ssq = 0.f;

  // depth-1 prefetch for g = 0
  int idxp = indx[jj * GPB_];
  float sxv = (tid < 64) ? xb[(size_t)idxp * 64 + tid] : 0.f;
  int nbr = knn[(size_t)gidbase * 32 + r8];

#pragma unroll 1
  for (int g = 0; g < GPB_; ++g) {
    const int gid = gidbase + g;
    if (tid < 64) sx[tid] = sxv;
    __syncthreads();                         // A: sx visible; prior dls reads done

    // stage d = x[nbr] - sx as bf16 into dls (coalesced: 8 lanes per row)
    {
      const float* xrow = xb + (size_t)nbr * 64 + c8;
      const float4 xa = *(const float4*)(xrow);
      const float4 xc = *(const float4*)(xrow + 4);
      const float4 sa = *(const float4*)(sx + c8);
      const float4 sc = *(const float4*)(sx + c8 + 4);
      uint2 lo, hi;
      lo.x = bfpair(xa.x - sa.x, xa.y - sa.y);
      lo.y = bfpair(xa.z - sa.z, xa.w - sa.w);
      hi.x = bfpair(xc.x - sc.x, xc.y - sc.y);
      hi.y = bfpair(xc.z - sc.z, xc.w - sc.w);
      *(uint2*)&dls[r8 * 68 + c8] = lo;      // byte addr 136*r8+16k: 8B-aligned
      *(uint2*)&dls[r8 * 68 + c8 + 4] = hi;
    }
    if (tid < 16) {                          // pack sx -> bf16 (post-A)
      const float4 sv = *(const float4*)(sx + tid * 4);
      uint2 p;
      p.x = bfpair(sv.x, sv.y);
      p.y = bfpair(sv.z, sv.w);
      *(uint2*)&sxb[tid * 4] = p;
    }

    // prefetch g+1 chain (overlaps this group's MFMA; independent of LDS)
    if (g + 1 < GPB_) {
      const int s1n = jj * GPB_ + g + 1;
      const int idx1 = indx[s1n];
      sxv = (tid < 64) ? xb[(size_t)idx1 * 64 + tid] : 0.f;
      nbr = knn[(size_t)(gid + 1) * 32 + r8];
    }
    __syncthreads();                         // B: dls + sxb ready

    // A-frags: t<4 from sxb (k<64), t>=4 from dls (k>=64)
    bf8 af[8];
#pragma unroll
    for (int t = 0; t < 4; ++t) {
      union { bf8 v; uint2 u[2]; } fa;
      fa.u[0] = *(const uint2*)&sxb[t * 16 + q2 * 8];
      fa.u[1] = *(const uint2*)&sxb[t * 16 + q2 * 8 + 4];
      af[t] = fa.v;
    }
#pragma unroll
    for (int t = 0; t < 4; ++t) {
      union { bf8 v; uint2 u[2]; } fa;
      fa.u[0] = *(const uint2*)&dls[m * 68 + t * 16 + q2 * 8];
      fa.u[1] = *(const uint2*)&dls[m * 68 + t * 16 + q2 * 8 + 4];
      af[4 + t] = fa.v;
    }

    f32x16 acc;
#pragma unroll
    for (int r = 0; r < 16; ++r) acc[r] = b1c;
#pragma unroll
    for (int t = 0; t < 8; ++t)
      acc = __builtin_amdgcn_mfma_f32_32x32x16_bf16(af[t], bf1[t], acc, 0, 0, 0);

    if constexpr (PHASE == 1) {
#pragma unroll
      for (int r = 0; r < 16; ++r) {
        const float v = acc[r];
        sum += v;
        ssq = fmaf(v, v, ssq);
      }
    } else {
      // bn1 + relu -> h1 bf16 in LDS (C-layout scatter, row stride 136)
#pragma unroll
      for (int r = 0; r < 16; ++r) {
        const float hv = fmaxf(0.f, fmaf(acc[r], s1, t1));
        const int row = (r & 3) + ((r >> 2) << 3) + (q2 << 2);
        h1[row * 136 + col] = (unsigned short)bf1u(hv);
      }
      __syncthreads();                       // C: h1 ready

      f32x16 acc2;
#pragma unroll
      for (int r = 0; r < 16; ++r) acc2[r] = b2v;
#pragma unroll
      for (int t = 0; t < 8; ++t) {
        const bf8 a2 = *(const bf8*)&h1[m * 136 + t * 16 + q2 * 8];
        acc2 = __builtin_amdgcn_mfma_f32_32x32x16_bf16(a2, bf2[t], acc2, 0, 0, 0);
      }

      float mx = -1e30f;
#pragma unroll
      for (int r = 0; r < 16; ++r) {
        const float v = acc2[r];
        sum += v;
        ssq = fmaf(v, v, ssq);
        mx = fmaxf(mx, v);
      }
      mx = fmaxf(mx, __shfl_xor(mx, 32, 64));
      if (lane < 32) mout[(size_t)gid * 128 + col] = mx;
    }
  }

  // channel partials: each channel owned by exactly one wave
  sum += __shfl_xor(sum, 32, 64);
  ssq += __shfl_xor(ssq, 32, 64);
  if (lane < 32) {
    part[blockIdx.x * 256 + col] = sum;
    part[blockIdx.x * 256 + 128 + col] = ssq;
  }
}

// ---------------- stats reduce stage 1: 64 blocks, f64 partial sums ----------
__global__ __launch_bounds__(256) void kred1(const float* __restrict__ part,
                                             double* __restrict__ dbuf) {
  const int blk = blockIdx.x;                // 0..63: rows 32*blk..32*blk+31
  const int c = threadIdx.x;                 // 0..255 (128 sums | 128 ssqs)
  const float* p = part + (size_t)blk * 32 * 256 + c;
  double acc = 0.0;
#pragma unroll 8
  for (int r = 0; r < 32; ++r) acc += (double)p[r * 256];
  dbuf[blk * 256 + c] = acc;
}

// ---------------- stats reduce stage 2: finalize scale/shift -----------------
__global__ __launch_bounds__(256) void kred2(const double* __restrict__ dbuf,
                                             const float* __restrict__ gam,
                                             const float* __restrict__ bet,
                                             float* __restrict__ st) {
  __shared__ double sS[256];
  const int c = threadIdx.x;
  double acc = 0.0;
#pragma unroll 8
  for (int i = 0; i < 64; ++i) acc += dbuf[i * 256 + c];
  sS[c] = acc;
  __syncthreads();
  if (c < 128) {
    const double Sv = sS[c], SSv = sS[128 + c];
    const double cnt = 524288.0;             // B*S*K
    const double mean = Sv / cnt;
    const double var = SSv / cnt - mean * mean;
    const double scale = (double)gam[c] / sqrt(var + 1e-5);
    st[c] = (float)scale;
    st[128 + c] = (float)((double)bet[c] - mean * scale);
  }
}

// ---------------- final: out = relu(scale2 * max_k(y2) + shift2) -------------
__global__ __launch_bounds__(256) void kout(const float* __restrict__ m,
                                            const float* __restrict__ st2,
                                            float* __restrict__ out) {
  const int e4 = blockIdx.x * 256 + threadIdx.x;  // 524288 float4s
  const int o0 = (e4 & 31) * 4;
  const float4 v = ((const float4*)m)[e4];
  const float4 sc = *(const float4*)&st2[o0];
  const float4 sh = *(const float4*)&st2[128 + o0];
  float4 r;
  r.x = fmaxf(0.f, fmaf(v.x, sc.x, sh.x));
  r.y = fmaxf(0.f, fmaf(v.y, sc.y, sh.y));
  r.z = fmaxf(0.f, fmaf(v.z, sc.z, sh.z));
  r.w = fmaxf(0.f, fmaf(v.w, sc.w, sh.w));
  ((float4*)out)[e4] = r;
}

extern "C" void kernel_launch(void* const* d_in, const int* in_sizes, int n_in,
                              void* d_out, int out_size, void* d_ws, size_t ws_size,
                              hipStream_t stream) {
  (void)in_sizes; (void)n_in; (void)out_size; (void)ws_size;
  const float* x    = (const float*)d_in[0];
  const float* coor = (const float*)d_in[1];
  const int*   indx = (const int*)d_in[2];
  const float* w1   = (const float*)d_in[3];
  const float* b1   = (const float*)d_in[4];
  const float* g1   = (const float*)d_in[5];
  const float* be1  = (const float*)d_in[6];
  const float* w2   = (const float*)d_in[7];
  const float* b2   = (const float*)d_in[8];
  const float* g2   = (const float*)d_in[9];
  const float* be2  = (const float*)d_in[10];
  float* out = (float*)d_out;

  char* ws = (char*)d_ws;
  int*            knn   = (int*)(ws + 0);
  float*          mbuf  = (float*)(ws + 2097152);
  float*          part1 = (float*)(ws + 10485760);
  float4*         coor4 = (float4*)(ws + 10485760); // aliases part1 (disjoint lifetime)
  float*          part2 = (float*)(ws + 12582912);
  unsigned short* w1b   = (unsigned short*)(ws + 14680064);
  unsigned short* w2b   = (unsigned short*)(ws + 14712832);
  float*          st1   = (float*)(ws + 14745600);
  float*          st2   = (float*)(ws + 14746624);
  double*         dbuf  = (double*)(ws + 14747648);

  float* outc = out + 2097152;   // sampled_coor region of d_out

  kprep<<<576, 256, 0, stream>>>(w1, w2, coor, indx, w1b, w2b, outc, coor4);
  kknn<<<16384, 256, 0, stream>>>(coor4, indx, knn);
  kphase<1><<<2048, 256, 0, stream>>>(x, indx, knn, b1, w1b, w2b, b2, nullptr,
                                      part1, nullptr);
  kred1<<<64, 256, 0, stream>>>(part1, dbuf);
  kred2<<<1, 256, 0, stream>>>(dbuf, g1, be1, st1);
  kphase<2><<<2048, 256, 0, stream>>>(x, indx, knn, b1, w1b, w2b, b2, st1,
                                      part2, mbuf);
  kred1<<<64, 256, 0, stream>>>(part2, dbuf);
  kred2<<<1, 256, 0, stream>>>(dbuf, g2, be2, st2);
  kout<<<2048, 256, 0, stream>>>(mbuf, st2, out);
}